// Round 11
// baseline (266.572 us; speedup 1.0000x reference)
//
#include <hip/hip_runtime.h>
#include <cstdint>

// GNN: 2-layer GraphSAGE (mean aggr, L2-normalize) + BatchNorm(train) + ReLU.
// N=100000 nodes, E=800000 edges, C: 128 -> 128 -> 47.
//
// Round 21: R20's two stacked changes (8-edge gather1, lb(256,6)) were
// neutral-to-negative (265.3 vs 261.8) -> both reverted to R19. New single
// lever: kill the k_bmeta dispatch (1-block kernel on the serial critical
// path). Fused into k_prep via last-block-reduction: hist blocks store
// counts, __threadfence, atomicAdd(done); the last block (acquire fence)
// does the column-sum + scan + bucketStart/gcur writes, overlapped with
// prep's xcast tail. done-counter zeroed by a 4B hipMemsetAsync (capture-
// safe; the harness itself uses hipMemsetAsync). 7 dispatches total.

typedef __attribute__((ext_vector_type(8))) short s8v;
typedef __attribute__((ext_vector_type(4))) short s4v;
typedef __attribute__((ext_vector_type(4))) float fx4;

#define CSR_CHUNK 8192
#define CSR_SH 8            // 256 nodes per bucket
#define CSR_NBPAD 512       // padded bucket count (NB = ceil(n/256) = 391)
#define CSR_BUFCAP 3072     // LDS srcbuf cap per bucket (mean 2046, +20 sigma)

static __device__ __forceinline__ float bf2f(unsigned short h) {
    union { unsigned int u; float f; } c; c.u = (unsigned int)h << 16; return c.f;
}
static __device__ __forceinline__ unsigned short f2bf(float f) {
    union { float f; unsigned int u; } c; c.f = f;
    unsigned int u = c.u;
    return (unsigned short)((u + 0x7FFF + ((u >> 16) & 1)) >> 16);   // RNE
}

// ---- merged prep: x->bf16 | weight casts | stats zero | bcount histograms
// | (last hist block) bucket scan. ----
__global__ __launch_bounds__(256) void k_prep(
        const float* __restrict__ x, const float* __restrict__ w1l,
        const float* __restrict__ w1r, const float* __restrict__ w2l,
        const float* __restrict__ w2r, const int* __restrict__ ei,
        unsigned short* __restrict__ xb, unsigned short* __restrict__ wB1,
        unsigned short* __restrict__ wB2p, float* __restrict__ stats,
        int* __restrict__ counts, int* __restrict__ bucketStart,
        int* __restrict__ gcur, int* __restrict__ done,
        int n, int nE, int prepBlocks, int NB) {
    __shared__ int shm[1792];
    __shared__ int isLast;
    int t = threadIdx.x;
    if ((int)blockIdx.x >= prepBlocks) {
        int nCh = (nE + CSR_CHUNK - 1) / CSR_CHUNK;
        int* hist = shm;
        int chunk = blockIdx.x - prepBlocks;
        hist[t] = 0; hist[t + 256] = 0;
        __syncthreads();
        int e0 = chunk * CSR_CHUNK;
        int e1 = min(e0 + CSR_CHUNK, nE);
        for (int e = e0 + t; e < e1; e += 256)
            atomicAdd(&hist[ei[nE + e] >> CSR_SH], 1);
        __syncthreads();
        counts[chunk * CSR_NBPAD + t] = hist[t];
        counts[chunk * CSR_NBPAD + t + 256] = hist[t + 256];
        // ---- elect last hist block; it performs the bucket scan ----
        __threadfence();    // release: counts visible device-wide
        if (t == 0) isLast = (atomicAdd(done, 1) == nCh - 1);
        __syncthreads();
        if (!isLast) return;
        __threadfence();    // acquire: observe all chunks' counts
        int* tot  = shm;          // [512] (aliases hist -- consumed)
        int* tot2 = shm + 512;    // [512]
        int* sh   = shm + 1024;   // [256]
        int* bs   = shm + 1280;   // [512]
        int tl = t & 127, g = t >> 7;
        int half = (nCh + 1) >> 1;
        int c0 = g * half, c1 = min(nCh, c0 + half);
        int4 s4 = {0, 0, 0, 0};
        for (int c = c0; c < c1; ++c) {
            int4 v = *(const int4*)(counts + (size_t)c * CSR_NBPAD + tl * 4);
            s4.x += v.x; s4.y += v.y; s4.z += v.z; s4.w += v.w;
        }
        __syncthreads();    // hist fully consumed -> safe to overwrite as tot
        *(int4*)((g ? tot2 : tot) + tl * 4) = s4;
        __syncthreads();
        tot[t] += tot2[t];
        tot[t + 256] += tot2[t + 256];
        __syncthreads();
        int pairSum = tot[2 * t] + tot[2 * t + 1];
        sh[t] = pairSum;
        __syncthreads();
        for (int off = 1; off < 256; off <<= 1) {
            int add = (t >= off) ? sh[t - off] : 0;
            __syncthreads();
            sh[t] += add;
            __syncthreads();
        }
        int excl = sh[t] - pairSum;
        bs[2 * t] = excl;
        bs[2 * t + 1] = excl + tot[2 * t];
        __syncthreads();
        for (int b = t; b <= NB; b += 256) bucketStart[b] = bs[b];
        for (int b = t; b < CSR_NBPAD; b += 256) gcur[b] = bs[b];
        return;
    }
    int idx = blockIdx.x * 256 + t;
    int nx = n * 16;
    if (idx < nx) {
        float4 a = ((const float4*)x)[idx * 2];
        float4 b = ((const float4*)x)[idx * 2 + 1];
        union { s8v v; unsigned short u[8]; } o;
        o.u[0] = f2bf(a.x); o.u[1] = f2bf(a.y); o.u[2] = f2bf(a.z); o.u[3] = f2bf(a.w);
        o.u[4] = f2bf(b.x); o.u[5] = f2bf(b.y); o.u[6] = f2bf(b.z); o.u[7] = f2bf(b.w);
        ((s8v*)xb)[idx] = o.v;
        return;
    }
    idx -= nx;
    if (idx < 32768) {
        int j = idx >> 8, k = idx & 255;
        float v = (k < 128) ? w1l[j * 128 + k] : w1r[j * 128 + (k - 128)];
        wB1[idx] = f2bf(v);
        return;
    }
    idx -= 32768;
    if (idx < 16384) {
        int j = idx >> 7, k = idx & 127;
        float v = 0.f;
        if (j < 47)      v = w2l[j * 128 + k];
        else if (j < 94) v = w2r[(j - 47) * 128 + k];
        wB2p[idx] = f2bf(v);
        return;
    }
    idx -= 16384;
    if (idx < 2048) stats[idx] = 0.f;   // 8-way split stats copies
}

__global__ __launch_bounds__(256) void k_bfill(
        const int* __restrict__ ei, const int* __restrict__ counts,
        int* __restrict__ gcur, int* __restrict__ pairs, int nE) {
    __shared__ int cur[CSR_NBPAD];
    int t = threadIdx.x;
    #pragma unroll
    for (int i = 0; i < 2; ++i) {
        int b = t + i * 256;
        int h = counts[blockIdx.x * CSR_NBPAD + b];
        cur[b] = h ? atomicAdd(&gcur[b], h) : 0;
    }
    __syncthreads();
    int e0 = blockIdx.x * CSR_CHUNK;
    int e1 = min(e0 + CSR_CHUNK, nE);
    for (int e = e0 + t; e < e1; e += 256) {
        int s = ei[e];
        int d = ei[nE + e];
        int p = atomicAdd(&cur[d >> CSR_SH], 1);
        pairs[p] = (s << 8) | (d & 255);
    }
}

__global__ __launch_bounds__(256) void k_csr(
        const int* __restrict__ pairs, const int* __restrict__ bucketStart,
        int* __restrict__ deg, int* __restrict__ rowStart,
        int* __restrict__ srcIdx, int n) {
    __shared__ int cnt[256], scn[256], cur[256];
    __shared__ int buf[CSR_BUFCAP];
    int t = threadIdx.x;
    int bkt = blockIdx.x;
    int eBeg = bucketStart[bkt], eEnd = bucketStart[bkt + 1];
    int node0 = bkt << CSR_SH;
    cnt[t] = 0;
    __syncthreads();
    for (int e = eBeg + t; e < eEnd; e += 256)
        atomicAdd(&cnt[pairs[e] & 255], 1);
    __syncthreads();
    int myc = cnt[t];
    scn[t] = myc;
    __syncthreads();
    for (int off = 1; off < 256; off <<= 1) {
        int add = (t >= off) ? scn[t - off] : 0;
        __syncthreads();
        scn[t] += add;
        __syncthreads();
    }
    int excl = scn[t] - myc;
    cur[t] = excl;
    int node = node0 + t;
    if (node < n) { deg[node] = myc; rowStart[node] = eBeg + excl; }
    __syncthreads();
    for (int e = eBeg + t; e < eEnd; e += 256) {
        int pk = pairs[e];
        int p = atomicAdd(&cur[pk & 255], 1);
        int src = pk >> 8;
        if (p < CSR_BUFCAP) buf[p] = src;
        else srcIdx[eBeg + p] = src;   // statistically never at this size
    }
    __syncthreads();
    int m = min(eEnd - eBeg, CSR_BUFCAP);
    for (int i = t; i < m; i += 256) srcIdx[eBeg + i] = buf[i];
}

// ---- layer-1 gather (bf16): 16 lanes/node, lane owns 8 ch; 4-edge unroll.
__global__ __launch_bounds__(256) void k_gather1(
        const unsigned short* __restrict__ xb, const int* __restrict__ rowStart,
        const int* __restrict__ deg, const int* __restrict__ srcIdx,
        unsigned short* __restrict__ aggb, int n) {
    int t = threadIdx.x;
    int q = t & 15, grp = t >> 4;
    int node = blockIdx.x * 16 + grp;
    if (node >= n) return;
    int beg = rowStart[node];
    int d = deg[node];
    int end = beg + d;
    float a0[8] = {}, a1[8] = {}, a2[8] = {}, a3[8] = {};
    int e = beg;
    for (; e + 4 <= end; e += 4) {
        int s0 = srcIdx[e], s1v = srcIdx[e + 1], s2 = srcIdx[e + 2], s3 = srcIdx[e + 3];
        s8v v0 = *(const s8v*)(xb + (size_t)s0 * 128 + q * 8);
        s8v v1 = *(const s8v*)(xb + (size_t)s1v * 128 + q * 8);
        s8v v2 = *(const s8v*)(xb + (size_t)s2 * 128 + q * 8);
        s8v v3 = *(const s8v*)(xb + (size_t)s3 * 128 + q * 8);
        #pragma unroll
        for (int u = 0; u < 8; ++u) {
            a0[u] += bf2f((unsigned short)v0[u]);
            a1[u] += bf2f((unsigned short)v1[u]);
            a2[u] += bf2f((unsigned short)v2[u]);
            a3[u] += bf2f((unsigned short)v3[u]);
        }
    }
    for (; e < end; ++e) {
        s8v v0 = *(const s8v*)(xb + (size_t)srcIdx[e] * 128 + q * 8);
        #pragma unroll
        for (int u = 0; u < 8; ++u) a0[u] += bf2f((unsigned short)v0[u]);
    }
    float ic = 1.0f / fmaxf((float)d, 1.0f);
    union { s8v v; unsigned short u[8]; } o;
    #pragma unroll
    for (int u = 0; u < 8; ++u)
        o.u[u] = f2bf((a0[u] + a1[u] + a2[u] + a3[u]) * ic);
    *(s8v*)(aggb + (size_t)node * 128 + q * 8) = o.v;
}

// Async 16B global->LDS (gfx950). Dest is wave-uniform base + lane*16;
// our LDS layout is lane-linear so per-lane dest == HW dest.
#define GLL16(GSRC, LDST) \
    __builtin_amdgcn_global_load_lds( \
        (__attribute__((address_space(1))) void*)(void*)(GSRC), \
        (__attribute__((address_space(3))) void*)(LDST), 16, 0, 0)

// ---- GEMM1 (bf16 MFMA): block 64x128, K=256 (aggb then xb), BK=32,
// 8 rounds. Grid 1563, launch_bounds(256,4) -> 4+ blocks/CU.
__global__ __launch_bounds__(256, 4) void k_gemm1(
        const unsigned short* __restrict__ xb, const unsigned short* __restrict__ aggb,
        const unsigned short* __restrict__ wB1, const float* __restrict__ b1l,
        unsigned short* __restrict__ s1b, float* __restrict__ stats, int n) {
    __shared__ __align__(16) unsigned short xs[64 * 32];    // 4KB [row][32]
    __shared__ __align__(16) unsigned short ws[128 * 32];   // 8KB [j][32]
    __shared__ float norm2[128];   // [64][2]
    __shared__ float invn[64];
    __shared__ float statS[256];   // [128][2]
    __shared__ float statQ[256];   // [128][2]
    int t = threadIdx.x;
    int w = t >> 6, L = t & 63;
    int q = L >> 4, lm = L & 15;
    int wr0 = (w >> 1) * 32;     // wave row base (0 or 32)
    int wc0 = (w & 1) * 64;      // wave col base (0 or 64)
    int r0 = blockIdx.x * 64;

    fx4 acc[2][4];
    fx4 z4 = {0.f, 0.f, 0.f, 0.f};
    #pragma unroll
    for (int r = 0; r < 2; ++r)
        #pragma unroll
        for (int c = 0; c < 4; ++c) acc[r][c] = z4;

    for (int kt = 0; kt < 8; ++kt) {
        const unsigned short* src = (kt < 4) ? aggb : xb;
        int kbase = (kt & 3) * 32;
        __syncthreads();   // previous round's reads done -> buffers reusable
        {
            // xs: 256 x 16B chunks (1/thread)
            int row = t >> 2, p = t & 3;
            int sl = p ^ ((row >> 1) & 3);
            int gr = r0 + row; gr = gr < n ? gr : (n - 1);
            GLL16(src + (size_t)gr * 128 + kbase + sl * 8, &xs[t * 8]);
            // ws: 512 x 16B chunks (2/thread)
            #pragma unroll
            for (int it = 0; it < 2; ++it) {
                int i = t + it * 256;
                int wrow = i >> 2, wp = i & 3;
                int wsl = wp ^ ((wrow >> 1) & 3);
                GLL16(wB1 + (size_t)wrow * 256 + kt * 32 + wsl * 8, &ws[i * 8]);
            }
        }
        __syncthreads();   // full vmcnt(0) drain before s_barrier -> DMA landed
        s8v af[2], bfr[4];
        #pragma unroll
        for (int r = 0; r < 2; ++r) {
            int row = wr0 + r * 16 + lm;
            af[r] = *(const s8v*)&xs[row * 32 + ((q ^ ((row >> 1) & 3)) << 3)];
        }
        #pragma unroll
        for (int c = 0; c < 4; ++c) {
            int row = wc0 + c * 16 + lm;
            bfr[c] = *(const s8v*)&ws[row * 32 + ((q ^ ((row >> 1) & 3)) << 3)];
        }
        #pragma unroll
        for (int r = 0; r < 2; ++r)
            #pragma unroll
            for (int c = 0; c < 4; ++c)
                acc[r][c] = __builtin_amdgcn_mfma_f32_16x16x32_bf16(af[r], bfr[c], acc[r][c], 0, 0, 0);
    }

    // ---- epilogue: bias -> row L2-norm -> scale -> bf16 store -> BN stats
    float bj[4];
    #pragma unroll
    for (int c = 0; c < 4; ++c) bj[c] = b1l[wc0 + c * 16 + lm];
    #pragma unroll
    for (int r = 0; r < 2; ++r)
        #pragma unroll
        for (int c = 0; c < 4; ++c) acc[r][c] += bj[c];

    fx4 pr[2];
    #pragma unroll
    for (int r = 0; r < 2; ++r) {
        fx4 p = acc[r][0] * acc[r][0];
        #pragma unroll
        for (int c = 1; c < 4; ++c) p += acc[r][c] * acc[r][c];
        #pragma unroll
        for (int off = 1; off <= 8; off <<= 1)
            #pragma unroll
            for (int i2 = 0; i2 < 4; ++i2) p[i2] += __shfl_xor(p[i2], off, 64);
        pr[r] = p;
    }

    __syncthreads();
    if (lm == 0) {
        #pragma unroll
        for (int r = 0; r < 2; ++r)
            #pragma unroll
            for (int i = 0; i < 4; ++i)
                norm2[(wr0 + r * 16 + q * 4 + i) * 2 + (w & 1)] = pr[r][i];
    }
    __syncthreads();
    if (t < 64) {
        float s = norm2[t * 2] + norm2[t * 2 + 1];
        invn[t] = 1.0f / fmaxf(sqrtf(s), 1e-12f);
    }
    __syncthreads();

    float cS[4] = {}, cQ[4] = {};
    #pragma unroll
    for (int r = 0; r < 2; ++r) {
        int rowb = wr0 + r * 16 + q * 4;
        fx4 iv = *(const fx4*)&invn[rowb];
        #pragma unroll
        for (int c = 0; c < 4; ++c) {
            fx4 v = acc[r][c] * iv;
            int col = wc0 + c * 16 + lm;
            #pragma unroll
            for (int i = 0; i < 4; ++i) {
                int gr = r0 + rowb + i;
                if (gr < n) {
                    s1b[(size_t)gr * 128 + col] = f2bf(v[i]);
                    cS[c] += v[i];
                    cQ[c] += v[i] * v[i];
                }
            }
        }
    }
    #pragma unroll
    for (int off = 16; off <= 32; off <<= 1)
        #pragma unroll
        for (int c = 0; c < 4; ++c) {
            cS[c] += __shfl_xor(cS[c], off, 64);
            cQ[c] += __shfl_xor(cQ[c], off, 64);
        }
    if (q == 0) {
        #pragma unroll
        for (int c = 0; c < 4; ++c) {
            int col = wc0 + c * 16 + lm;
            statS[col * 2 + (w >> 1)] = cS[c];
            statQ[col * 2 + (w >> 1)] = cQ[c];
        }
    }
    __syncthreads();
    if (t < 128) {
        float* sp = stats + ((int)blockIdx.x & 7) * 256;   // 8-way split
        atomicAdd(&sp[t],       statS[t * 2] + statS[t * 2 + 1]);
        atomicAdd(&sp[128 + t], statQ[t * 2] + statQ[t * 2 + 1]);
    }
}

// ---- GEMM2 (bf16 MFMA) with inline BN finalize. Block 64x128, BK=32,
// 4 rounds, grid 1563, launch_bounds(256,4). BN coeffs from 8 split copies.
__global__ __launch_bounds__(256, 4) void k_gemm2(
        const unsigned short* __restrict__ s1b, const unsigned short* __restrict__ wB2p,
        const float* __restrict__ stats, const float* __restrict__ gamma,
        const float* __restrict__ beta, const float* __restrict__ b2l,
        unsigned short* __restrict__ y2b, float* __restrict__ rbuf, int n) {
    __shared__ __align__(16) unsigned short xs[64 * 32];    // 4KB
    __shared__ __align__(16) unsigned short ws[128 * 32];   // 8KB
    __shared__ __align__(16) float abuf[128];
    __shared__ __align__(16) float bbuf[128];
    int t = threadIdx.x;
    int w = t >> 6, L = t & 63;
    int q = L >> 4, lm = L & 15;
    int wr0 = (w >> 1) * 32, wc0 = (w & 1) * 64;
    int r0 = blockIdx.x * 64;

    if (t < 128) {
        float s = 0.f, qv = 0.f;
        #pragma unroll
        for (int k = 0; k < 8; ++k) {
            s  += stats[k * 256 + t];
            qv += stats[k * 256 + 128 + t];
        }
        float fn = (float)n;
        float mean = s / fn;
        float var = qv / fn - mean * mean;   // biased variance
        float istd = rsqrtf(var + 1e-5f);
        float a = gamma[t] * istd;
        abuf[t] = a;
        bbuf[t] = beta[t] - mean * a;
    }
    __syncthreads();   // abuf/bbuf visible to all

    fx4 acc[2][4];
    fx4 z4 = {0.f, 0.f, 0.f, 0.f};
    #pragma unroll
    for (int r = 0; r < 2; ++r)
        #pragma unroll
        for (int c = 0; c < 4; ++c) acc[r][c] = z4;

    for (int kt = 0; kt < 4; ++kt) {
        int kbase = kt * 32;
        __syncthreads();
        {
            int row = t >> 2, p = t & 3;
            int sl = p ^ ((row >> 1) & 3);
            int gr = r0 + row; gr = gr < n ? gr : (n - 1);
            GLL16(s1b + (size_t)gr * 128 + kbase + sl * 8, &xs[t * 8]);
            #pragma unroll
            for (int it = 0; it < 2; ++it) {
                int i = t + it * 256;
                int wrow = i >> 2, wp = i & 3;
                int wsl = wp ^ ((wrow >> 1) & 3);
                GLL16(wB2p + (size_t)wrow * 128 + kbase + wsl * 8, &ws[i * 8]);
            }
        }
        __syncthreads();   // DMA drained -> tiles visible
        int kb = kbase + q * 8;
        fx4 a0 = *(const fx4*)&abuf[kb];
        fx4 a1 = *(const fx4*)&abuf[kb + 4];
        fx4 b0 = *(const fx4*)&bbuf[kb];
        fx4 b1 = *(const fx4*)&bbuf[kb + 4];
        s8v af[2], bfr[4];
        #pragma unroll
        for (int r = 0; r < 2; ++r) {
            int row = wr0 + r * 16 + lm;
            s8v sv = *(const s8v*)&xs[row * 32 + ((q ^ ((row >> 1) & 3)) << 3)];
            union { s8v v; unsigned short u[8]; } o;
            #pragma unroll
            for (int u = 0; u < 4; ++u) {
                float h0 = fmaxf(fmaf(a0[u], bf2f((unsigned short)sv[u]), b0[u]), 0.f);
                float h1 = fmaxf(fmaf(a1[u], bf2f((unsigned short)sv[u + 4]), b1[u]), 0.f);
                o.u[u]     = f2bf(h0);
                o.u[u + 4] = f2bf(h1);
            }
            af[r] = o.v;
        }
        #pragma unroll
        for (int c = 0; c < 4; ++c) {
            int row = wc0 + c * 16 + lm;
            bfr[c] = *(const s8v*)&ws[row * 32 + ((q ^ ((row >> 1) & 3)) << 3)];
        }
        #pragma unroll
        for (int r = 0; r < 2; ++r)
            #pragma unroll
            for (int c = 0; c < 4; ++c)
                acc[r][c] = __builtin_amdgcn_mfma_f32_16x16x32_bf16(af[r], bfr[c], acc[r][c], 0, 0, 0);
    }

    // epilogue: y2b bf16 stride 64 (j<47) / rbuf fp32 stride 48 + b2l (j 47..93)
    #pragma unroll
    for (int c = 0; c < 4; ++c) {
        int col = wc0 + c * 16 + lm;
        float bb = (col >= 47 && col < 94) ? b2l[col - 47] : 0.f;
        #pragma unroll
        for (int r = 0; r < 2; ++r) {
            int rowb = wr0 + r * 16 + q * 4;
            #pragma unroll
            for (int i = 0; i < 4; ++i) {
                int gr = r0 + rowb + i;
                if (gr >= n) continue;
                float v = acc[r][c][i];
                if (col < 47)      y2b[(size_t)gr * 64 + col] = f2bf(v);
                else if (col < 94) rbuf[(size_t)gr * 48 + (col - 47)] = v + bb;
            }
        }
    }
}

// ---- layer-2 gather + combine + L2-norm. 16 lanes/node (lane owns 4 ch),
// 16 nodes/block, 8-edge unroll -> 4 independent load chains per wave.
__global__ __launch_bounds__(256) void k_gather2_final(
        const unsigned short* __restrict__ y2b, const float* __restrict__ rbuf,
        const int* __restrict__ rowStart, const int* __restrict__ deg,
        const int* __restrict__ srcIdx, float* __restrict__ out, int n) {
    int t = threadIdx.x;
    int q = t & 15, grp = t >> 4;
    int node = blockIdx.x * 16 + grp;
    if (node >= n) return;
    int beg = rowStart[node];
    int d = deg[node];
    int end = beg + d;
    float acc[4] = {0.f, 0.f, 0.f, 0.f};
    int e = beg;
    for (; e + 8 <= end; e += 8) {
        int s0 = srcIdx[e],     s1v = srcIdx[e + 1];
        int s2 = srcIdx[e + 2], s3  = srcIdx[e + 3];
        int s4 = srcIdx[e + 4], s5  = srcIdx[e + 5];
        int s6 = srcIdx[e + 6], s7  = srcIdx[e + 7];
        s4v v0 = *(const s4v*)(y2b + (size_t)s0 * 64 + q * 4);
        s4v v1 = *(const s4v*)(y2b + (size_t)s1v * 64 + q * 4);
        s4v v2 = *(const s4v*)(y2b + (size_t)s2 * 64 + q * 4);
        s4v v3 = *(const s4v*)(y2b + (size_t)s3 * 64 + q * 4);
        s4v v4 = *(const s4v*)(y2b + (size_t)s4 * 64 + q * 4);
        s4v v5 = *(const s4v*)(y2b + (size_t)s5 * 64 + q * 4);
        s4v v6 = *(const s4v*)(y2b + (size_t)s6 * 64 + q * 4);
        s4v v7 = *(const s4v*)(y2b + (size_t)s7 * 64 + q * 4);
        #pragma unroll
        for (int u = 0; u < 4; ++u) {
            acc[u] += (bf2f((unsigned short)v0[u]) + bf2f((unsigned short)v1[u]))
                    + (bf2f((unsigned short)v2[u]) + bf2f((unsigned short)v3[u]))
                    + (bf2f((unsigned short)v4[u]) + bf2f((unsigned short)v5[u]))
                    + (bf2f((unsigned short)v6[u]) + bf2f((unsigned short)v7[u]));
        }
    }
    for (; e + 4 <= end; e += 4) {
        int s0 = srcIdx[e],     s1v = srcIdx[e + 1];
        int s2 = srcIdx[e + 2], s3  = srcIdx[e + 3];
        s4v v0 = *(const s4v*)(y2b + (size_t)s0 * 64 + q * 4);
        s4v v1 = *(const s4v*)(y2b + (size_t)s1v * 64 + q * 4);
        s4v v2 = *(const s4v*)(y2b + (size_t)s2 * 64 + q * 4);
        s4v v3 = *(const s4v*)(y2b + (size_t)s3 * 64 + q * 4);
        #pragma unroll
        for (int u = 0; u < 4; ++u)
            acc[u] += (bf2f((unsigned short)v0[u]) + bf2f((unsigned short)v1[u]))
                    + (bf2f((unsigned short)v2[u]) + bf2f((unsigned short)v3[u]));
    }
    for (; e < end; ++e) {
        s4v v0 = *(const s4v*)(y2b + (size_t)srcIdx[e] * 64 + q * 4);
        #pragma unroll
        for (int u = 0; u < 4; ++u) acc[u] += bf2f((unsigned short)v0[u]);
    }
    float ic = 1.0f / fmaxf((float)d, 1.0f);
    fx4 rb = *(const fx4*)(rbuf + (size_t)node * 48 + q * 4);
    float vi[4];
    float ss = 0.f;
    #pragma unroll
    for (int u = 0; u < 4; ++u) {
        int ch = q * 4 + u;
        float v = (ch < 47) ? (acc[u] * ic + rb[u]) : 0.f;   // select masks pad (NaN-safe)
        vi[u] = v;
        ss += v * v;
    }
    #pragma unroll
    for (int off = 1; off <= 8; off <<= 1) ss += __shfl_xor(ss, off, 64);
    float inv = 1.0f / fmaxf(sqrtf(ss), 1e-12f);
    #pragma unroll
    for (int u = 0; u < 4; ++u) {
        int ch = q * 4 + u;
        if (ch < 47) out[(size_t)node * 47 + ch] = vi[u] * inv;
    }
}

extern "C" void kernel_launch(void* const* d_in, const int* in_sizes, int n_in,
                              void* d_out, int out_size, void* d_ws, size_t ws_size,
                              hipStream_t stream) {
    const float* x     = (const float*)d_in[0];
    const int*   ei    = (const int*)d_in[1];
    const float* w1l   = (const float*)d_in[2];
    const float* b1l   = (const float*)d_in[3];
    const float* w1r   = (const float*)d_in[4];
    const float* gamma = (const float*)d_in[5];
    const float* beta  = (const float*)d_in[6];
    const float* w2l   = (const float*)d_in[7];
    const float* b2l   = (const float*)d_in[8];
    const float* w2r   = (const float*)d_in[9];
    float* out = (float*)d_out;

    int n  = in_sizes[0] / 128;   // 100000
    int nE = in_sizes[1] / 2;     // 800000

    int NB  = (n + 255) >> 8;                    // 391 buckets
    int nCh = (nE + CSR_CHUNK - 1) / CSR_CHUNK;  // 98 chunks

    // ---- workspace layout ----
    // deg[n](int) | stats[2048](f32, 8 copies) | rowStart[n] | meta[n]
    // | srcIdx[nE] | xb[128n bf16] | aggb[128n bf16] | s1b[128n bf16]
    // | wB1 | wB2p
    // meta: counts[nCh*512] then bucketStart at +60000, gcur[512] at +61000,
    // done-counter at +61600.
    // pairs[nE] overlays s1b (dead until gemm1).
    // y2b[64n bf16, 1 line/row] + rbuf[48n f32] overlay xb+aggb.
    int* deg       = (int*)d_ws;
    float* stats   = (float*)(deg + n);
    int* rowStart  = (int*)(stats + 2048);
    int* meta      = rowStart + n;
    int* srcIdx    = meta + n;
    unsigned short* xb   = (unsigned short*)(srcIdx + nE);
    unsigned short* aggb = xb + (size_t)n * 128;
    unsigned short* s1b  = aggb + (size_t)n * 128;
    unsigned short* wB1  = s1b + (size_t)n * 128;
    unsigned short* wB2p = wB1 + 32768;
    int* counts      = meta;
    int* bucketStart = meta + 60000;
    int* gcur        = meta + 61000;
    int* done        = meta + 61600;
    int* pairs       = (int*)s1b;             // packed (src<<8)|(dst&255)
    unsigned short* y2b = xb;                 // stride 64 shorts (128B/row)
    float* rbuf = (float*)(y2b + (size_t)n * 64);   // stride 48 f32

    int prepTotal  = n * 16 + 32768 + 16384 + 2048;
    int prepBlocks = (prepTotal + 255) / 256;

    // 0: zero the last-block election counter (workspace is poisoned)
    hipMemsetAsync(done, 0, sizeof(int), stream);
    // 1: prep (xcast | weight casts | stats zero | bcount | bucket scan)
    k_prep<<<prepBlocks + nCh, 256, 0, stream>>>(
        x, w1l, w1r, w2l, w2r, ei, xb, wB1, wB2p, stats, counts,
        bucketStart, gcur, done, n, nE, prepBlocks, NB);
    // 2-3: CSR build (bucketed counting sort, runtime range reservation)
    k_bfill<<<nCh, 256, 0, stream>>>(ei, counts, gcur, pairs, nE);
    k_csr<<<NB, 256, 0, stream>>>(pairs, bucketStart, deg, rowStart, srcIdx, n);
    // 4-5: layer 1
    k_gather1<<<(n + 15) / 16, 256, 0, stream>>>(xb, rowStart, deg, srcIdx, aggb, n);
    k_gemm1<<<(n + 63) / 64, 256, 0, stream>>>(xb, aggb, wB1, b1l, s1b, stats, n);
    // 6-7: layer 2 (BN finalize inlined in gemm2)
    k_gemm2<<<(n + 63) / 64, 256, 0, stream>>>(
        s1b, wB2p, stats, gamma, beta, b2l, y2b, rbuf, n);
    k_gather2_final<<<(n + 15) / 16, 256, 0, stream>>>(y2b, rbuf, rowStart, deg, srcIdx, out, n);
}

// Round 12
// 263.677 us; speedup vs baseline: 1.0110x; 1.0110x over previous
//
#include <hip/hip_runtime.h>
#include <cstdint>

// GNN: 2-layer GraphSAGE (mean aggr, L2-normalize) + BatchNorm(train) + ReLU.
// N=100000 nodes, E=800000 edges, C: 128 -> 128 -> 47.
//
// Round 22: k_prep was top dispatch (44.6us) with duration-weighted
// occupancy 20% -- the 98 histogram blocks (launched LAST) + the elected
// scan block formed a serial tail after the wide xcast bulk drained.
// Fix: ORDERING ONLY -- hist blocks first (blockIdx < nCh), xcast after.
// Hist phase + scan now run concurrently under the xcast bulk.
// Everything else identical to R21 (R19-best gemm/gather configs).

typedef __attribute__((ext_vector_type(8))) short s8v;
typedef __attribute__((ext_vector_type(4))) short s4v;
typedef __attribute__((ext_vector_type(4))) float fx4;

#define CSR_CHUNK 8192
#define CSR_SH 8            // 256 nodes per bucket
#define CSR_NBPAD 512       // padded bucket count (NB = ceil(n/256) = 391)
#define CSR_BUFCAP 3072     // LDS srcbuf cap per bucket (mean 2046, +20 sigma)

static __device__ __forceinline__ float bf2f(unsigned short h) {
    union { unsigned int u; float f; } c; c.u = (unsigned int)h << 16; return c.f;
}
static __device__ __forceinline__ unsigned short f2bf(float f) {
    union { float f; unsigned int u; } c; c.f = f;
    unsigned int u = c.u;
    return (unsigned short)((u + 0x7FFF + ((u >> 16) & 1)) >> 16);   // RNE
}

// ---- merged prep: bcount histograms FIRST (+ elected bucket scan),
// then x->bf16 | weight casts | stats zero. ----
__global__ __launch_bounds__(256) void k_prep(
        const float* __restrict__ x, const float* __restrict__ w1l,
        const float* __restrict__ w1r, const float* __restrict__ w2l,
        const float* __restrict__ w2r, const int* __restrict__ ei,
        unsigned short* __restrict__ xb, unsigned short* __restrict__ wB1,
        unsigned short* __restrict__ wB2p, float* __restrict__ stats,
        int* __restrict__ counts, int* __restrict__ bucketStart,
        int* __restrict__ gcur, int* __restrict__ done,
        int n, int nE, int nCh, int NB) {
    __shared__ int shm[1792];
    __shared__ int isLast;
    int t = threadIdx.x;
    if ((int)blockIdx.x < nCh) {
        int* hist = shm;
        int chunk = blockIdx.x;
        hist[t] = 0; hist[t + 256] = 0;
        __syncthreads();
        int e0 = chunk * CSR_CHUNK;
        int e1 = min(e0 + CSR_CHUNK, nE);
        for (int e = e0 + t; e < e1; e += 256)
            atomicAdd(&hist[ei[nE + e] >> CSR_SH], 1);
        __syncthreads();
        counts[chunk * CSR_NBPAD + t] = hist[t];
        counts[chunk * CSR_NBPAD + t + 256] = hist[t + 256];
        // ---- elect last hist block; it performs the bucket scan ----
        __threadfence();    // release: counts visible device-wide
        if (t == 0) isLast = (atomicAdd(done, 1) == nCh - 1);
        __syncthreads();
        if (!isLast) return;
        __threadfence();    // acquire: observe all chunks' counts
        int* tot  = shm;          // [512] (aliases hist -- consumed)
        int* tot2 = shm + 512;    // [512]
        int* sh   = shm + 1024;   // [256]
        int* bs   = shm + 1280;   // [512]
        int tl = t & 127, g = t >> 7;
        int half = (nCh + 1) >> 1;
        int c0 = g * half, c1 = min(nCh, c0 + half);
        int4 s4 = {0, 0, 0, 0};
        for (int c = c0; c < c1; ++c) {
            int4 v = *(const int4*)(counts + (size_t)c * CSR_NBPAD + tl * 4);
            s4.x += v.x; s4.y += v.y; s4.z += v.z; s4.w += v.w;
        }
        __syncthreads();    // hist fully consumed -> safe to overwrite as tot
        *(int4*)((g ? tot2 : tot) + tl * 4) = s4;
        __syncthreads();
        tot[t] += tot2[t];
        tot[t + 256] += tot2[t + 256];
        __syncthreads();
        int pairSum = tot[2 * t] + tot[2 * t + 1];
        sh[t] = pairSum;
        __syncthreads();
        for (int off = 1; off < 256; off <<= 1) {
            int add = (t >= off) ? sh[t - off] : 0;
            __syncthreads();
            sh[t] += add;
            __syncthreads();
        }
        int excl = sh[t] - pairSum;
        bs[2 * t] = excl;
        bs[2 * t + 1] = excl + tot[2 * t];
        __syncthreads();
        for (int b = t; b <= NB; b += 256) bucketStart[b] = bs[b];
        for (int b = t; b < CSR_NBPAD; b += 256) gcur[b] = bs[b];
        return;
    }
    int idx = (blockIdx.x - nCh) * 256 + t;
    int nx = n * 16;
    if (idx < nx) {
        float4 a = ((const float4*)x)[idx * 2];
        float4 b = ((const float4*)x)[idx * 2 + 1];
        union { s8v v; unsigned short u[8]; } o;
        o.u[0] = f2bf(a.x); o.u[1] = f2bf(a.y); o.u[2] = f2bf(a.z); o.u[3] = f2bf(a.w);
        o.u[4] = f2bf(b.x); o.u[5] = f2bf(b.y); o.u[6] = f2bf(b.z); o.u[7] = f2bf(b.w);
        ((s8v*)xb)[idx] = o.v;
        return;
    }
    idx -= nx;
    if (idx < 32768) {
        int j = idx >> 8, k = idx & 255;
        float v = (k < 128) ? w1l[j * 128 + k] : w1r[j * 128 + (k - 128)];
        wB1[idx] = f2bf(v);
        return;
    }
    idx -= 32768;
    if (idx < 16384) {
        int j = idx >> 7, k = idx & 127;
        float v = 0.f;
        if (j < 47)      v = w2l[j * 128 + k];
        else if (j < 94) v = w2r[(j - 47) * 128 + k];
        wB2p[idx] = f2bf(v);
        return;
    }
    idx -= 16384;
    if (idx < 2048) stats[idx] = 0.f;   // 8-way split stats copies
}

__global__ __launch_bounds__(256) void k_bfill(
        const int* __restrict__ ei, const int* __restrict__ counts,
        int* __restrict__ gcur, int* __restrict__ pairs, int nE) {
    __shared__ int cur[CSR_NBPAD];
    int t = threadIdx.x;
    #pragma unroll
    for (int i = 0; i < 2; ++i) {
        int b = t + i * 256;
        int h = counts[blockIdx.x * CSR_NBPAD + b];
        cur[b] = h ? atomicAdd(&gcur[b], h) : 0;
    }
    __syncthreads();
    int e0 = blockIdx.x * CSR_CHUNK;
    int e1 = min(e0 + CSR_CHUNK, nE);
    for (int e = e0 + t; e < e1; e += 256) {
        int s = ei[e];
        int d = ei[nE + e];
        int p = atomicAdd(&cur[d >> CSR_SH], 1);
        pairs[p] = (s << 8) | (d & 255);
    }
}

__global__ __launch_bounds__(256) void k_csr(
        const int* __restrict__ pairs, const int* __restrict__ bucketStart,
        int* __restrict__ deg, int* __restrict__ rowStart,
        int* __restrict__ srcIdx, int n) {
    __shared__ int cnt[256], scn[256], cur[256];
    __shared__ int buf[CSR_BUFCAP];
    int t = threadIdx.x;
    int bkt = blockIdx.x;
    int eBeg = bucketStart[bkt], eEnd = bucketStart[bkt + 1];
    int node0 = bkt << CSR_SH;
    cnt[t] = 0;
    __syncthreads();
    for (int e = eBeg + t; e < eEnd; e += 256)
        atomicAdd(&cnt[pairs[e] & 255], 1);
    __syncthreads();
    int myc = cnt[t];
    scn[t] = myc;
    __syncthreads();
    for (int off = 1; off < 256; off <<= 1) {
        int add = (t >= off) ? scn[t - off] : 0;
        __syncthreads();
        scn[t] += add;
        __syncthreads();
    }
    int excl = scn[t] - myc;
    cur[t] = excl;
    int node = node0 + t;
    if (node < n) { deg[node] = myc; rowStart[node] = eBeg + excl; }
    __syncthreads();
    for (int e = eBeg + t; e < eEnd; e += 256) {
        int pk = pairs[e];
        int p = atomicAdd(&cur[pk & 255], 1);
        int src = pk >> 8;
        if (p < CSR_BUFCAP) buf[p] = src;
        else srcIdx[eBeg + p] = src;   // statistically never at this size
    }
    __syncthreads();
    int m = min(eEnd - eBeg, CSR_BUFCAP);
    for (int i = t; i < m; i += 256) srcIdx[eBeg + i] = buf[i];
}

// ---- layer-1 gather (bf16): 16 lanes/node, lane owns 8 ch; 4-edge unroll.
__global__ __launch_bounds__(256) void k_gather1(
        const unsigned short* __restrict__ xb, const int* __restrict__ rowStart,
        const int* __restrict__ deg, const int* __restrict__ srcIdx,
        unsigned short* __restrict__ aggb, int n) {
    int t = threadIdx.x;
    int q = t & 15, grp = t >> 4;
    int node = blockIdx.x * 16 + grp;
    if (node >= n) return;
    int beg = rowStart[node];
    int d = deg[node];
    int end = beg + d;
    float a0[8] = {}, a1[8] = {}, a2[8] = {}, a3[8] = {};
    int e = beg;
    for (; e + 4 <= end; e += 4) {
        int s0 = srcIdx[e], s1v = srcIdx[e + 1], s2 = srcIdx[e + 2], s3 = srcIdx[e + 3];
        s8v v0 = *(const s8v*)(xb + (size_t)s0 * 128 + q * 8);
        s8v v1 = *(const s8v*)(xb + (size_t)s1v * 128 + q * 8);
        s8v v2 = *(const s8v*)(xb + (size_t)s2 * 128 + q * 8);
        s8v v3 = *(const s8v*)(xb + (size_t)s3 * 128 + q * 8);
        #pragma unroll
        for (int u = 0; u < 8; ++u) {
            a0[u] += bf2f((unsigned short)v0[u]);
            a1[u] += bf2f((unsigned short)v1[u]);
            a2[u] += bf2f((unsigned short)v2[u]);
            a3[u] += bf2f((unsigned short)v3[u]);
        }
    }
    for (; e < end; ++e) {
        s8v v0 = *(const s8v*)(xb + (size_t)srcIdx[e] * 128 + q * 8);
        #pragma unroll
        for (int u = 0; u < 8; ++u) a0[u] += bf2f((unsigned short)v0[u]);
    }
    float ic = 1.0f / fmaxf((float)d, 1.0f);
    union { s8v v; unsigned short u[8]; } o;
    #pragma unroll
    for (int u = 0; u < 8; ++u)
        o.u[u] = f2bf((a0[u] + a1[u] + a2[u] + a3[u]) * ic);
    *(s8v*)(aggb + (size_t)node * 128 + q * 8) = o.v;
}

// Async 16B global->LDS (gfx950). Dest is wave-uniform base + lane*16;
// our LDS layout is lane-linear so per-lane dest == HW dest.
#define GLL16(GSRC, LDST) \
    __builtin_amdgcn_global_load_lds( \
        (__attribute__((address_space(1))) void*)(void*)(GSRC), \
        (__attribute__((address_space(3))) void*)(LDST), 16, 0, 0)

// ---- GEMM1 (bf16 MFMA): block 64x128, K=256 (aggb then xb), BK=32,
// 8 rounds. Grid 1563, launch_bounds(256,4) -> 4+ blocks/CU.
__global__ __launch_bounds__(256, 4) void k_gemm1(
        const unsigned short* __restrict__ xb, const unsigned short* __restrict__ aggb,
        const unsigned short* __restrict__ wB1, const float* __restrict__ b1l,
        unsigned short* __restrict__ s1b, float* __restrict__ stats, int n) {
    __shared__ __align__(16) unsigned short xs[64 * 32];    // 4KB [row][32]
    __shared__ __align__(16) unsigned short ws[128 * 32];   // 8KB [j][32]
    __shared__ float norm2[128];   // [64][2]
    __shared__ float invn[64];
    __shared__ float statS[256];   // [128][2]
    __shared__ float statQ[256];   // [128][2]
    int t = threadIdx.x;
    int w = t >> 6, L = t & 63;
    int q = L >> 4, lm = L & 15;
    int wr0 = (w >> 1) * 32;     // wave row base (0 or 32)
    int wc0 = (w & 1) * 64;      // wave col base (0 or 64)
    int r0 = blockIdx.x * 64;

    fx4 acc[2][4];
    fx4 z4 = {0.f, 0.f, 0.f, 0.f};
    #pragma unroll
    for (int r = 0; r < 2; ++r)
        #pragma unroll
        for (int c = 0; c < 4; ++c) acc[r][c] = z4;

    for (int kt = 0; kt < 8; ++kt) {
        const unsigned short* src = (kt < 4) ? aggb : xb;
        int kbase = (kt & 3) * 32;
        __syncthreads();   // previous round's reads done -> buffers reusable
        {
            // xs: 256 x 16B chunks (1/thread)
            int row = t >> 2, p = t & 3;
            int sl = p ^ ((row >> 1) & 3);
            int gr = r0 + row; gr = gr < n ? gr : (n - 1);
            GLL16(src + (size_t)gr * 128 + kbase + sl * 8, &xs[t * 8]);
            // ws: 512 x 16B chunks (2/thread)
            #pragma unroll
            for (int it = 0; it < 2; ++it) {
                int i = t + it * 256;
                int wrow = i >> 2, wp = i & 3;
                int wsl = wp ^ ((wrow >> 1) & 3);
                GLL16(wB1 + (size_t)wrow * 256 + kt * 32 + wsl * 8, &ws[i * 8]);
            }
        }
        __syncthreads();   // full vmcnt(0) drain before s_barrier -> DMA landed
        s8v af[2], bfr[4];
        #pragma unroll
        for (int r = 0; r < 2; ++r) {
            int row = wr0 + r * 16 + lm;
            af[r] = *(const s8v*)&xs[row * 32 + ((q ^ ((row >> 1) & 3)) << 3)];
        }
        #pragma unroll
        for (int c = 0; c < 4; ++c) {
            int row = wc0 + c * 16 + lm;
            bfr[c] = *(const s8v*)&ws[row * 32 + ((q ^ ((row >> 1) & 3)) << 3)];
        }
        #pragma unroll
        for (int r = 0; r < 2; ++r)
            #pragma unroll
            for (int c = 0; c < 4; ++c)
                acc[r][c] = __builtin_amdgcn_mfma_f32_16x16x32_bf16(af[r], bfr[c], acc[r][c], 0, 0, 0);
    }

    // ---- epilogue: bias -> row L2-norm -> scale -> bf16 store -> BN stats
    float bj[4];
    #pragma unroll
    for (int c = 0; c < 4; ++c) bj[c] = b1l[wc0 + c * 16 + lm];
    #pragma unroll
    for (int r = 0; r < 2; ++r)
        #pragma unroll
        for (int c = 0; c < 4; ++c) acc[r][c] += bj[c];

    fx4 pr[2];
    #pragma unroll
    for (int r = 0; r < 2; ++r) {
        fx4 p = acc[r][0] * acc[r][0];
        #pragma unroll
        for (int c = 1; c < 4; ++c) p += acc[r][c] * acc[r][c];
        #pragma unroll
        for (int off = 1; off <= 8; off <<= 1)
            #pragma unroll
            for (int i2 = 0; i2 < 4; ++i2) p[i2] += __shfl_xor(p[i2], off, 64);
        pr[r] = p;
    }

    __syncthreads();
    if (lm == 0) {
        #pragma unroll
        for (int r = 0; r < 2; ++r)
            #pragma unroll
            for (int i = 0; i < 4; ++i)
                norm2[(wr0 + r * 16 + q * 4 + i) * 2 + (w & 1)] = pr[r][i];
    }
    __syncthreads();
    if (t < 64) {
        float s = norm2[t * 2] + norm2[t * 2 + 1];
        invn[t] = 1.0f / fmaxf(sqrtf(s), 1e-12f);
    }
    __syncthreads();

    float cS[4] = {}, cQ[4] = {};
    #pragma unroll
    for (int r = 0; r < 2; ++r) {
        int rowb = wr0 + r * 16 + q * 4;
        fx4 iv = *(const fx4*)&invn[rowb];
        #pragma unroll
        for (int c = 0; c < 4; ++c) {
            fx4 v = acc[r][c] * iv;
            int col = wc0 + c * 16 + lm;
            #pragma unroll
            for (int i = 0; i < 4; ++i) {
                int gr = r0 + rowb + i;
                if (gr < n) {
                    s1b[(size_t)gr * 128 + col] = f2bf(v[i]);
                    cS[c] += v[i];
                    cQ[c] += v[i] * v[i];
                }
            }
        }
    }
    #pragma unroll
    for (int off = 16; off <= 32; off <<= 1)
        #pragma unroll
        for (int c = 0; c < 4; ++c) {
            cS[c] += __shfl_xor(cS[c], off, 64);
            cQ[c] += __shfl_xor(cQ[c], off, 64);
        }
    if (q == 0) {
        #pragma unroll
        for (int c = 0; c < 4; ++c) {
            int col = wc0 + c * 16 + lm;
            statS[col * 2 + (w >> 1)] = cS[c];
            statQ[col * 2 + (w >> 1)] = cQ[c];
        }
    }
    __syncthreads();
    if (t < 128) {
        float* sp = stats + ((int)blockIdx.x & 7) * 256;   // 8-way split
        atomicAdd(&sp[t],       statS[t * 2] + statS[t * 2 + 1]);
        atomicAdd(&sp[128 + t], statQ[t * 2] + statQ[t * 2 + 1]);
    }
}

// ---- GEMM2 (bf16 MFMA) with inline BN finalize. Block 64x128, BK=32,
// 4 rounds, grid 1563, launch_bounds(256,4). BN coeffs from 8 split copies.
__global__ __launch_bounds__(256, 4) void k_gemm2(
        const unsigned short* __restrict__ s1b, const unsigned short* __restrict__ wB2p,
        const float* __restrict__ stats, const float* __restrict__ gamma,
        const float* __restrict__ beta, const float* __restrict__ b2l,
        unsigned short* __restrict__ y2b, float* __restrict__ rbuf, int n) {
    __shared__ __align__(16) unsigned short xs[64 * 32];    // 4KB
    __shared__ __align__(16) unsigned short ws[128 * 32];   // 8KB
    __shared__ __align__(16) float abuf[128];
    __shared__ __align__(16) float bbuf[128];
    int t = threadIdx.x;
    int w = t >> 6, L = t & 63;
    int q = L >> 4, lm = L & 15;
    int wr0 = (w >> 1) * 32, wc0 = (w & 1) * 64;
    int r0 = blockIdx.x * 64;

    if (t < 128) {
        float s = 0.f, qv = 0.f;
        #pragma unroll
        for (int k = 0; k < 8; ++k) {
            s  += stats[k * 256 + t];
            qv += stats[k * 256 + 128 + t];
        }
        float fn = (float)n;
        float mean = s / fn;
        float var = qv / fn - mean * mean;   // biased variance
        float istd = rsqrtf(var + 1e-5f);
        float a = gamma[t] * istd;
        abuf[t] = a;
        bbuf[t] = beta[t] - mean * a;
    }
    __syncthreads();   // abuf/bbuf visible to all

    fx4 acc[2][4];
    fx4 z4 = {0.f, 0.f, 0.f, 0.f};
    #pragma unroll
    for (int r = 0; r < 2; ++r)
        #pragma unroll
        for (int c = 0; c < 4; ++c) acc[r][c] = z4;

    for (int kt = 0; kt < 4; ++kt) {
        int kbase = kt * 32;
        __syncthreads();
        {
            int row = t >> 2, p = t & 3;
            int sl = p ^ ((row >> 1) & 3);
            int gr = r0 + row; gr = gr < n ? gr : (n - 1);
            GLL16(s1b + (size_t)gr * 128 + kbase + sl * 8, &xs[t * 8]);
            #pragma unroll
            for (int it = 0; it < 2; ++it) {
                int i = t + it * 256;
                int wrow = i >> 2, wp = i & 3;
                int wsl = wp ^ ((wrow >> 1) & 3);
                GLL16(wB2p + (size_t)wrow * 128 + kbase + wsl * 8, &ws[i * 8]);
            }
        }
        __syncthreads();   // DMA drained -> tiles visible
        int kb = kbase + q * 8;
        fx4 a0 = *(const fx4*)&abuf[kb];
        fx4 a1 = *(const fx4*)&abuf[kb + 4];
        fx4 b0 = *(const fx4*)&bbuf[kb];
        fx4 b1 = *(const fx4*)&bbuf[kb + 4];
        s8v af[2], bfr[4];
        #pragma unroll
        for (int r = 0; r < 2; ++r) {
            int row = wr0 + r * 16 + lm;
            s8v sv = *(const s8v*)&xs[row * 32 + ((q ^ ((row >> 1) & 3)) << 3)];
            union { s8v v; unsigned short u[8]; } o;
            #pragma unroll
            for (int u = 0; u < 4; ++u) {
                float h0 = fmaxf(fmaf(a0[u], bf2f((unsigned short)sv[u]), b0[u]), 0.f);
                float h1 = fmaxf(fmaf(a1[u], bf2f((unsigned short)sv[u + 4]), b1[u]), 0.f);
                o.u[u]     = f2bf(h0);
                o.u[u + 4] = f2bf(h1);
            }
            af[r] = o.v;
        }
        #pragma unroll
        for (int c = 0; c < 4; ++c) {
            int row = wc0 + c * 16 + lm;
            bfr[c] = *(const s8v*)&ws[row * 32 + ((q ^ ((row >> 1) & 3)) << 3)];
        }
        #pragma unroll
        for (int r = 0; r < 2; ++r)
            #pragma unroll
            for (int c = 0; c < 4; ++c)
                acc[r][c] = __builtin_amdgcn_mfma_f32_16x16x32_bf16(af[r], bfr[c], acc[r][c], 0, 0, 0);
    }

    // epilogue: y2b bf16 stride 64 (j<47) / rbuf fp32 stride 48 + b2l (j 47..93)
    #pragma unroll
    for (int c = 0; c < 4; ++c) {
        int col = wc0 + c * 16 + lm;
        float bb = (col >= 47 && col < 94) ? b2l[col - 47] : 0.f;
        #pragma unroll
        for (int r = 0; r < 2; ++r) {
            int rowb = wr0 + r * 16 + q * 4;
            #pragma unroll
            for (int i = 0; i < 4; ++i) {
                int gr = r0 + rowb + i;
                if (gr >= n) continue;
                float v = acc[r][c][i];
                if (col < 47)      y2b[(size_t)gr * 64 + col] = f2bf(v);
                else if (col < 94) rbuf[(size_t)gr * 48 + (col - 47)] = v + bb;
            }
        }
    }
}

// ---- layer-2 gather + combine + L2-norm. 16 lanes/node (lane owns 4 ch),
// 16 nodes/block, 8-edge unroll -> 4 independent load chains per wave.
__global__ __launch_bounds__(256) void k_gather2_final(
        const unsigned short* __restrict__ y2b, const float* __restrict__ rbuf,
        const int* __restrict__ rowStart, const int* __restrict__ deg,
        const int* __restrict__ srcIdx, float* __restrict__ out, int n) {
    int t = threadIdx.x;
    int q = t & 15, grp = t >> 4;
    int node = blockIdx.x * 16 + grp;
    if (node >= n) return;
    int beg = rowStart[node];
    int d = deg[node];
    int end = beg + d;
    float acc[4] = {0.f, 0.f, 0.f, 0.f};
    int e = beg;
    for (; e + 8 <= end; e += 8) {
        int s0 = srcIdx[e],     s1v = srcIdx[e + 1];
        int s2 = srcIdx[e + 2], s3  = srcIdx[e + 3];
        int s4 = srcIdx[e + 4], s5  = srcIdx[e + 5];
        int s6 = srcIdx[e + 6], s7  = srcIdx[e + 7];
        s4v v0 = *(const s4v*)(y2b + (size_t)s0 * 64 + q * 4);
        s4v v1 = *(const s4v*)(y2b + (size_t)s1v * 64 + q * 4);
        s4v v2 = *(const s4v*)(y2b + (size_t)s2 * 64 + q * 4);
        s4v v3 = *(const s4v*)(y2b + (size_t)s3 * 64 + q * 4);
        s4v v4 = *(const s4v*)(y2b + (size_t)s4 * 64 + q * 4);
        s4v v5 = *(const s4v*)(y2b + (size_t)s5 * 64 + q * 4);
        s4v v6 = *(const s4v*)(y2b + (size_t)s6 * 64 + q * 4);
        s4v v7 = *(const s4v*)(y2b + (size_t)s7 * 64 + q * 4);
        #pragma unroll
        for (int u = 0; u < 4; ++u) {
            acc[u] += (bf2f((unsigned short)v0[u]) + bf2f((unsigned short)v1[u]))
                    + (bf2f((unsigned short)v2[u]) + bf2f((unsigned short)v3[u]))
                    + (bf2f((unsigned short)v4[u]) + bf2f((unsigned short)v5[u]))
                    + (bf2f((unsigned short)v6[u]) + bf2f((unsigned short)v7[u]));
        }
    }
    for (; e + 4 <= end; e += 4) {
        int s0 = srcIdx[e],     s1v = srcIdx[e + 1];
        int s2 = srcIdx[e + 2], s3  = srcIdx[e + 3];
        s4v v0 = *(const s4v*)(y2b + (size_t)s0 * 64 + q * 4);
        s4v v1 = *(const s4v*)(y2b + (size_t)s1v * 64 + q * 4);
        s4v v2 = *(const s4v*)(y2b + (size_t)s2 * 64 + q * 4);
        s4v v3 = *(const s4v*)(y2b + (size_t)s3 * 64 + q * 4);
        #pragma unroll
        for (int u = 0; u < 4; ++u)
            acc[u] += (bf2f((unsigned short)v0[u]) + bf2f((unsigned short)v1[u]))
                    + (bf2f((unsigned short)v2[u]) + bf2f((unsigned short)v3[u]));
    }
    for (; e < end; ++e) {
        s4v v0 = *(const s4v*)(y2b + (size_t)srcIdx[e] * 64 + q * 4);
        #pragma unroll
        for (int u = 0; u < 4; ++u) acc[u] += bf2f((unsigned short)v0[u]);
    }
    float ic = 1.0f / fmaxf((float)d, 1.0f);
    fx4 rb = *(const fx4*)(rbuf + (size_t)node * 48 + q * 4);
    float vi[4];
    float ss = 0.f;
    #pragma unroll
    for (int u = 0; u < 4; ++u) {
        int ch = q * 4 + u;
        float v = (ch < 47) ? (acc[u] * ic + rb[u]) : 0.f;   // select masks pad (NaN-safe)
        vi[u] = v;
        ss += v * v;
    }
    #pragma unroll
    for (int off = 1; off <= 8; off <<= 1) ss += __shfl_xor(ss, off, 64);
    float inv = 1.0f / fmaxf(sqrtf(ss), 1e-12f);
    #pragma unroll
    for (int u = 0; u < 4; ++u) {
        int ch = q * 4 + u;
        if (ch < 47) out[(size_t)node * 47 + ch] = vi[u] * inv;
    }
}

extern "C" void kernel_launch(void* const* d_in, const int* in_sizes, int n_in,
                              void* d_out, int out_size, void* d_ws, size_t ws_size,
                              hipStream_t stream) {
    const float* x     = (const float*)d_in[0];
    const int*   ei    = (const int*)d_in[1];
    const float* w1l   = (const float*)d_in[2];
    const float* b1l   = (const float*)d_in[3];
    const float* w1r   = (const float*)d_in[4];
    const float* gamma = (const float*)d_in[5];
    const float* beta  = (const float*)d_in[6];
    const float* w2l   = (const float*)d_in[7];
    const float* b2l   = (const float*)d_in[8];
    const float* w2r   = (const float*)d_in[9];
    float* out = (float*)d_out;

    int n  = in_sizes[0] / 128;   // 100000
    int nE = in_sizes[1] / 2;     // 800000

    int NB  = (n + 255) >> 8;                    // 391 buckets
    int nCh = (nE + CSR_CHUNK - 1) / CSR_CHUNK;  // 98 chunks

    // ---- workspace layout ----
    // deg[n](int) | stats[2048](f32, 8 copies) | rowStart[n] | meta[n]
    // | srcIdx[nE] | xb[128n bf16] | aggb[128n bf16] | s1b[128n bf16]
    // | wB1 | wB2p
    // meta: counts[nCh*512] then bucketStart at +60000, gcur[512] at +61000,
    // done-counter at +61600.
    // pairs[nE] overlays s1b (dead until gemm1).
    // y2b[64n bf16, 1 line/row] + rbuf[48n f32] overlay xb+aggb.
    int* deg       = (int*)d_ws;
    float* stats   = (float*)(deg + n);
    int* rowStart  = (int*)(stats + 2048);
    int* meta      = rowStart + n;
    int* srcIdx    = meta + n;
    unsigned short* xb   = (unsigned short*)(srcIdx + nE);
    unsigned short* aggb = xb + (size_t)n * 128;
    unsigned short* s1b  = aggb + (size_t)n * 128;
    unsigned short* wB1  = s1b + (size_t)n * 128;
    unsigned short* wB2p = wB1 + 32768;
    int* counts      = meta;
    int* bucketStart = meta + 60000;
    int* gcur        = meta + 61000;
    int* done        = meta + 61600;
    int* pairs       = (int*)s1b;             // packed (src<<8)|(dst&255)
    unsigned short* y2b = xb;                 // stride 64 shorts (128B/row)
    float* rbuf = (float*)(y2b + (size_t)n * 64);   // stride 48 f32

    int prepTotal  = n * 16 + 32768 + 16384 + 2048;
    int prepBlocks = (prepTotal + 255) / 256;

    // 0: zero the last-block election counter (workspace is poisoned)
    hipMemsetAsync(done, 0, sizeof(int), stream);
    // 1: prep (bcount + bucket scan FIRST | xcast | weight casts | stats zero)
    k_prep<<<nCh + prepBlocks, 256, 0, stream>>>(
        x, w1l, w1r, w2l, w2r, ei, xb, wB1, wB2p, stats, counts,
        bucketStart, gcur, done, n, nE, nCh, NB);
    // 2-3: CSR build (bucketed counting sort, runtime range reservation)
    k_bfill<<<nCh, 256, 0, stream>>>(ei, counts, gcur, pairs, nE);
    k_csr<<<NB, 256, 0, stream>>>(pairs, bucketStart, deg, rowStart, srcIdx, n);
    // 4-5: layer 1
    k_gather1<<<(n + 15) / 16, 256, 0, stream>>>(xb, rowStart, deg, srcIdx, aggb, n);
    k_gemm1<<<(n + 63) / 64, 256, 0, stream>>>(xb, aggb, wB1, b1l, s1b, stats, n);
    // 6-7: layer 2 (BN finalize inlined in gemm2)
    k_gemm2<<<(n + 63) / 64, 256, 0, stream>>>(
        s1b, wB2p, stats, gamma, beta, b2l, y2b, rbuf, n);
    k_gather2_final<<<(n + 15) / 16, 256, 0, stream>>>(y2b, rbuf, rowStart, deg, srcIdx, out, n);
}

// Round 13
// 261.326 us; speedup vs baseline: 1.0201x; 1.0090x over previous
//
#include <hip/hip_runtime.h>
#include <cstdint>

// GNN: 2-layer GraphSAGE (mean aggr, L2-normalize) + BatchNorm(train) + ReLU.
// N=100000 nodes, E=800000 edges, C: 128 -> 128 -> 47.
//
// Round 23: R22's hist-first reorder was NEUTRAL (k_prep 44.4us) -> tail
// theory wrong. New read of the counters: 6348 tiny blocks (2 loads + 1
// store each, ~1-2us lifetime), occupancy 26%, HBM 1.2TB/s, VALU 2.3% =>
// blocks drain faster than the command processor dispatches them (144
// blocks/us) -- CU starvation by DISPATCH RATE, not memory. Fix (G11):
// grid-stride the elementwise section over ~1950 persistent blocks; each
// thread now has 3-4 independent 32B load-pairs in flight. Hist blocks
// (first 98) + elected scan unchanged. Everything else identical to R22.

typedef __attribute__((ext_vector_type(8))) short s8v;
typedef __attribute__((ext_vector_type(4))) short s4v;
typedef __attribute__((ext_vector_type(4))) float fx4;

#define CSR_CHUNK 8192
#define CSR_SH 8            // 256 nodes per bucket
#define CSR_NBPAD 512       // padded bucket count (NB = ceil(n/256) = 391)
#define CSR_BUFCAP 3072     // LDS srcbuf cap per bucket (mean 2046, +20 sigma)
#define PREP_XBLOCKS 1950   // persistent grid-stride blocks for elementwise

static __device__ __forceinline__ float bf2f(unsigned short h) {
    union { unsigned int u; float f; } c; c.u = (unsigned int)h << 16; return c.f;
}
static __device__ __forceinline__ unsigned short f2bf(float f) {
    union { float f; unsigned int u; } c; c.f = f;
    unsigned int u = c.u;
    return (unsigned short)((u + 0x7FFF + ((u >> 16) & 1)) >> 16);   // RNE
}

// ---- merged prep: bcount histograms first (+ elected bucket scan), then
// grid-stride elementwise: x->bf16 | weight casts | stats zero. ----
__global__ __launch_bounds__(256) void k_prep(
        const float* __restrict__ x, const float* __restrict__ w1l,
        const float* __restrict__ w1r, const float* __restrict__ w2l,
        const float* __restrict__ w2r, const int* __restrict__ ei,
        unsigned short* __restrict__ xb, unsigned short* __restrict__ wB1,
        unsigned short* __restrict__ wB2p, float* __restrict__ stats,
        int* __restrict__ counts, int* __restrict__ bucketStart,
        int* __restrict__ gcur, int* __restrict__ done,
        int n, int nE, int nCh, int NB) {
    __shared__ int shm[1792];
    __shared__ int isLast;
    int t = threadIdx.x;
    if ((int)blockIdx.x < nCh) {
        int* hist = shm;
        int chunk = blockIdx.x;
        hist[t] = 0; hist[t + 256] = 0;
        __syncthreads();
        int e0 = chunk * CSR_CHUNK;
        int e1 = min(e0 + CSR_CHUNK, nE);
        for (int e = e0 + t; e < e1; e += 256)
            atomicAdd(&hist[ei[nE + e] >> CSR_SH], 1);
        __syncthreads();
        counts[chunk * CSR_NBPAD + t] = hist[t];
        counts[chunk * CSR_NBPAD + t + 256] = hist[t + 256];
        // ---- elect last hist block; it performs the bucket scan ----
        __threadfence();    // release: counts visible device-wide
        if (t == 0) isLast = (atomicAdd(done, 1) == nCh - 1);
        __syncthreads();
        if (!isLast) return;
        __threadfence();    // acquire: observe all chunks' counts
        int* tot  = shm;          // [512] (aliases hist -- consumed)
        int* tot2 = shm + 512;    // [512]
        int* sh   = shm + 1024;   // [256]
        int* bs   = shm + 1280;   // [512]
        int tl = t & 127, g = t >> 7;
        int half = (nCh + 1) >> 1;
        int c0 = g * half, c1 = min(nCh, c0 + half);
        int4 s4 = {0, 0, 0, 0};
        for (int c = c0; c < c1; ++c) {
            int4 v = *(const int4*)(counts + (size_t)c * CSR_NBPAD + tl * 4);
            s4.x += v.x; s4.y += v.y; s4.z += v.z; s4.w += v.w;
        }
        __syncthreads();    // hist fully consumed -> safe to overwrite as tot
        *(int4*)((g ? tot2 : tot) + tl * 4) = s4;
        __syncthreads();
        tot[t] += tot2[t];
        tot[t + 256] += tot2[t + 256];
        __syncthreads();
        int pairSum = tot[2 * t] + tot[2 * t + 1];
        sh[t] = pairSum;
        __syncthreads();
        for (int off = 1; off < 256; off <<= 1) {
            int add = (t >= off) ? sh[t - off] : 0;
            __syncthreads();
            sh[t] += add;
            __syncthreads();
        }
        int excl = sh[t] - pairSum;
        bs[2 * t] = excl;
        bs[2 * t + 1] = excl + tot[2 * t];
        __syncthreads();
        for (int b = t; b <= NB; b += 256) bucketStart[b] = bs[b];
        for (int b = t; b < CSR_NBPAD; b += 256) gcur[b] = bs[b];
        return;
    }
    // ---- grid-stride elementwise over the linear index space ----
    int nx = n * 16;
    int total = nx + 32768 + 16384 + 2048;
    int stride = (gridDim.x - nCh) * 256;
    for (int idx0 = ((int)blockIdx.x - nCh) * 256 + t; idx0 < total; idx0 += stride) {
        int idx = idx0;
        if (idx < nx) {
            float4 a = ((const float4*)x)[idx * 2];
            float4 b = ((const float4*)x)[idx * 2 + 1];
            union { s8v v; unsigned short u[8]; } o;
            o.u[0] = f2bf(a.x); o.u[1] = f2bf(a.y); o.u[2] = f2bf(a.z); o.u[3] = f2bf(a.w);
            o.u[4] = f2bf(b.x); o.u[5] = f2bf(b.y); o.u[6] = f2bf(b.z); o.u[7] = f2bf(b.w);
            ((s8v*)xb)[idx] = o.v;
            continue;
        }
        idx -= nx;
        if (idx < 32768) {
            int j = idx >> 8, k = idx & 255;
            float v = (k < 128) ? w1l[j * 128 + k] : w1r[j * 128 + (k - 128)];
            wB1[idx] = f2bf(v);
            continue;
        }
        idx -= 32768;
        if (idx < 16384) {
            int j = idx >> 7, k = idx & 127;
            float v = 0.f;
            if (j < 47)      v = w2l[j * 128 + k];
            else if (j < 94) v = w2r[(j - 47) * 128 + k];
            wB2p[idx] = f2bf(v);
            continue;
        }
        idx -= 16384;
        if (idx < 2048) stats[idx] = 0.f;   // 8-way split stats copies
    }
}

__global__ __launch_bounds__(256) void k_bfill(
        const int* __restrict__ ei, const int* __restrict__ counts,
        int* __restrict__ gcur, int* __restrict__ pairs, int nE) {
    __shared__ int cur[CSR_NBPAD];
    int t = threadIdx.x;
    #pragma unroll
    for (int i = 0; i < 2; ++i) {
        int b = t + i * 256;
        int h = counts[blockIdx.x * CSR_NBPAD + b];
        cur[b] = h ? atomicAdd(&gcur[b], h) : 0;
    }
    __syncthreads();
    int e0 = blockIdx.x * CSR_CHUNK;
    int e1 = min(e0 + CSR_CHUNK, nE);
    for (int e = e0 + t; e < e1; e += 256) {
        int s = ei[e];
        int d = ei[nE + e];
        int p = atomicAdd(&cur[d >> CSR_SH], 1);
        pairs[p] = (s << 8) | (d & 255);
    }
}

__global__ __launch_bounds__(256) void k_csr(
        const int* __restrict__ pairs, const int* __restrict__ bucketStart,
        int* __restrict__ deg, int* __restrict__ rowStart,
        int* __restrict__ srcIdx, int n) {
    __shared__ int cnt[256], scn[256], cur[256];
    __shared__ int buf[CSR_BUFCAP];
    int t = threadIdx.x;
    int bkt = blockIdx.x;
    int eBeg = bucketStart[bkt], eEnd = bucketStart[bkt + 1];
    int node0 = bkt << CSR_SH;
    cnt[t] = 0;
    __syncthreads();
    for (int e = eBeg + t; e < eEnd; e += 256)
        atomicAdd(&cnt[pairs[e] & 255], 1);
    __syncthreads();
    int myc = cnt[t];
    scn[t] = myc;
    __syncthreads();
    for (int off = 1; off < 256; off <<= 1) {
        int add = (t >= off) ? scn[t - off] : 0;
        __syncthreads();
        scn[t] += add;
        __syncthreads();
    }
    int excl = scn[t] - myc;
    cur[t] = excl;
    int node = node0 + t;
    if (node < n) { deg[node] = myc; rowStart[node] = eBeg + excl; }
    __syncthreads();
    for (int e = eBeg + t; e < eEnd; e += 256) {
        int pk = pairs[e];
        int p = atomicAdd(&cur[pk & 255], 1);
        int src = pk >> 8;
        if (p < CSR_BUFCAP) buf[p] = src;
        else srcIdx[eBeg + p] = src;   // statistically never at this size
    }
    __syncthreads();
    int m = min(eEnd - eBeg, CSR_BUFCAP);
    for (int i = t; i < m; i += 256) srcIdx[eBeg + i] = buf[i];
}

// ---- layer-1 gather (bf16): 16 lanes/node, lane owns 8 ch; 4-edge unroll.
__global__ __launch_bounds__(256) void k_gather1(
        const unsigned short* __restrict__ xb, const int* __restrict__ rowStart,
        const int* __restrict__ deg, const int* __restrict__ srcIdx,
        unsigned short* __restrict__ aggb, int n) {
    int t = threadIdx.x;
    int q = t & 15, grp = t >> 4;
    int node = blockIdx.x * 16 + grp;
    if (node >= n) return;
    int beg = rowStart[node];
    int d = deg[node];
    int end = beg + d;
    float a0[8] = {}, a1[8] = {}, a2[8] = {}, a3[8] = {};
    int e = beg;
    for (; e + 4 <= end; e += 4) {
        int s0 = srcIdx[e], s1v = srcIdx[e + 1], s2 = srcIdx[e + 2], s3 = srcIdx[e + 3];
        s8v v0 = *(const s8v*)(xb + (size_t)s0 * 128 + q * 8);
        s8v v1 = *(const s8v*)(xb + (size_t)s1v * 128 + q * 8);
        s8v v2 = *(const s8v*)(xb + (size_t)s2 * 128 + q * 8);
        s8v v3 = *(const s8v*)(xb + (size_t)s3 * 128 + q * 8);
        #pragma unroll
        for (int u = 0; u < 8; ++u) {
            a0[u] += bf2f((unsigned short)v0[u]);
            a1[u] += bf2f((unsigned short)v1[u]);
            a2[u] += bf2f((unsigned short)v2[u]);
            a3[u] += bf2f((unsigned short)v3[u]);
        }
    }
    for (; e < end; ++e) {
        s8v v0 = *(const s8v*)(xb + (size_t)srcIdx[e] * 128 + q * 8);
        #pragma unroll
        for (int u = 0; u < 8; ++u) a0[u] += bf2f((unsigned short)v0[u]);
    }
    float ic = 1.0f / fmaxf((float)d, 1.0f);
    union { s8v v; unsigned short u[8]; } o;
    #pragma unroll
    for (int u = 0; u < 8; ++u)
        o.u[u] = f2bf((a0[u] + a1[u] + a2[u] + a3[u]) * ic);
    *(s8v*)(aggb + (size_t)node * 128 + q * 8) = o.v;
}

// Async 16B global->LDS (gfx950). Dest is wave-uniform base + lane*16;
// our LDS layout is lane-linear so per-lane dest == HW dest.
#define GLL16(GSRC, LDST) \
    __builtin_amdgcn_global_load_lds( \
        (__attribute__((address_space(1))) void*)(void*)(GSRC), \
        (__attribute__((address_space(3))) void*)(LDST), 16, 0, 0)

// ---- GEMM1 (bf16 MFMA): block 64x128, K=256 (aggb then xb), BK=32,
// 8 rounds. Grid 1563, launch_bounds(256,4) -> 4+ blocks/CU.
__global__ __launch_bounds__(256, 4) void k_gemm1(
        const unsigned short* __restrict__ xb, const unsigned short* __restrict__ aggb,
        const unsigned short* __restrict__ wB1, const float* __restrict__ b1l,
        unsigned short* __restrict__ s1b, float* __restrict__ stats, int n) {
    __shared__ __align__(16) unsigned short xs[64 * 32];    // 4KB [row][32]
    __shared__ __align__(16) unsigned short ws[128 * 32];   // 8KB [j][32]
    __shared__ float norm2[128];   // [64][2]
    __shared__ float invn[64];
    __shared__ float statS[256];   // [128][2]
    __shared__ float statQ[256];   // [128][2]
    int t = threadIdx.x;
    int w = t >> 6, L = t & 63;
    int q = L >> 4, lm = L & 15;
    int wr0 = (w >> 1) * 32;     // wave row base (0 or 32)
    int wc0 = (w & 1) * 64;      // wave col base (0 or 64)
    int r0 = blockIdx.x * 64;

    fx4 acc[2][4];
    fx4 z4 = {0.f, 0.f, 0.f, 0.f};
    #pragma unroll
    for (int r = 0; r < 2; ++r)
        #pragma unroll
        for (int c = 0; c < 4; ++c) acc[r][c] = z4;

    for (int kt = 0; kt < 8; ++kt) {
        const unsigned short* src = (kt < 4) ? aggb : xb;
        int kbase = (kt & 3) * 32;
        __syncthreads();   // previous round's reads done -> buffers reusable
        {
            // xs: 256 x 16B chunks (1/thread)
            int row = t >> 2, p = t & 3;
            int sl = p ^ ((row >> 1) & 3);
            int gr = r0 + row; gr = gr < n ? gr : (n - 1);
            GLL16(src + (size_t)gr * 128 + kbase + sl * 8, &xs[t * 8]);
            // ws: 512 x 16B chunks (2/thread)
            #pragma unroll
            for (int it = 0; it < 2; ++it) {
                int i = t + it * 256;
                int wrow = i >> 2, wp = i & 3;
                int wsl = wp ^ ((wrow >> 1) & 3);
                GLL16(wB1 + (size_t)wrow * 256 + kt * 32 + wsl * 8, &ws[i * 8]);
            }
        }
        __syncthreads();   // full vmcnt(0) drain before s_barrier -> DMA landed
        s8v af[2], bfr[4];
        #pragma unroll
        for (int r = 0; r < 2; ++r) {
            int row = wr0 + r * 16 + lm;
            af[r] = *(const s8v*)&xs[row * 32 + ((q ^ ((row >> 1) & 3)) << 3)];
        }
        #pragma unroll
        for (int c = 0; c < 4; ++c) {
            int row = wc0 + c * 16 + lm;
            bfr[c] = *(const s8v*)&ws[row * 32 + ((q ^ ((row >> 1) & 3)) << 3)];
        }
        #pragma unroll
        for (int r = 0; r < 2; ++r)
            #pragma unroll
            for (int c = 0; c < 4; ++c)
                acc[r][c] = __builtin_amdgcn_mfma_f32_16x16x32_bf16(af[r], bfr[c], acc[r][c], 0, 0, 0);
    }

    // ---- epilogue: bias -> row L2-norm -> scale -> bf16 store -> BN stats
    float bj[4];
    #pragma unroll
    for (int c = 0; c < 4; ++c) bj[c] = b1l[wc0 + c * 16 + lm];
    #pragma unroll
    for (int r = 0; r < 2; ++r)
        #pragma unroll
        for (int c = 0; c < 4; ++c) acc[r][c] += bj[c];

    fx4 pr[2];
    #pragma unroll
    for (int r = 0; r < 2; ++r) {
        fx4 p = acc[r][0] * acc[r][0];
        #pragma unroll
        for (int c = 1; c < 4; ++c) p += acc[r][c] * acc[r][c];
        #pragma unroll
        for (int off = 1; off <= 8; off <<= 1)
            #pragma unroll
            for (int i2 = 0; i2 < 4; ++i2) p[i2] += __shfl_xor(p[i2], off, 64);
        pr[r] = p;
    }

    __syncthreads();
    if (lm == 0) {
        #pragma unroll
        for (int r = 0; r < 2; ++r)
            #pragma unroll
            for (int i = 0; i < 4; ++i)
                norm2[(wr0 + r * 16 + q * 4 + i) * 2 + (w & 1)] = pr[r][i];
    }
    __syncthreads();
    if (t < 64) {
        float s = norm2[t * 2] + norm2[t * 2 + 1];
        invn[t] = 1.0f / fmaxf(sqrtf(s), 1e-12f);
    }
    __syncthreads();

    float cS[4] = {}, cQ[4] = {};
    #pragma unroll
    for (int r = 0; r < 2; ++r) {
        int rowb = wr0 + r * 16 + q * 4;
        fx4 iv = *(const fx4*)&invn[rowb];
        #pragma unroll
        for (int c = 0; c < 4; ++c) {
            fx4 v = acc[r][c] * iv;
            int col = wc0 + c * 16 + lm;
            #pragma unroll
            for (int i = 0; i < 4; ++i) {
                int gr = r0 + rowb + i;
                if (gr < n) {
                    s1b[(size_t)gr * 128 + col] = f2bf(v[i]);
                    cS[c] += v[i];
                    cQ[c] += v[i] * v[i];
                }
            }
        }
    }
    #pragma unroll
    for (int off = 16; off <= 32; off <<= 1)
        #pragma unroll
        for (int c = 0; c < 4; ++c) {
            cS[c] += __shfl_xor(cS[c], off, 64);
            cQ[c] += __shfl_xor(cQ[c], off, 64);
        }
    if (q == 0) {
        #pragma unroll
        for (int c = 0; c < 4; ++c) {
            int col = wc0 + c * 16 + lm;
            statS[col * 2 + (w >> 1)] = cS[c];
            statQ[col * 2 + (w >> 1)] = cQ[c];
        }
    }
    __syncthreads();
    if (t < 128) {
        float* sp = stats + ((int)blockIdx.x & 7) * 256;   // 8-way split
        atomicAdd(&sp[t],       statS[t * 2] + statS[t * 2 + 1]);
        atomicAdd(&sp[128 + t], statQ[t * 2] + statQ[t * 2 + 1]);
    }
}

// ---- GEMM2 (bf16 MFMA) with inline BN finalize. Block 64x128, BK=32,
// 4 rounds, grid 1563, launch_bounds(256,4). BN coeffs from 8 split copies.
__global__ __launch_bounds__(256, 4) void k_gemm2(
        const unsigned short* __restrict__ s1b, const unsigned short* __restrict__ wB2p,
        const float* __restrict__ stats, const float* __restrict__ gamma,
        const float* __restrict__ beta, const float* __restrict__ b2l,
        unsigned short* __restrict__ y2b, float* __restrict__ rbuf, int n) {
    __shared__ __align__(16) unsigned short xs[64 * 32];    // 4KB
    __shared__ __align__(16) unsigned short ws[128 * 32];   // 8KB
    __shared__ __align__(16) float abuf[128];
    __shared__ __align__(16) float bbuf[128];
    int t = threadIdx.x;
    int w = t >> 6, L = t & 63;
    int q = L >> 4, lm = L & 15;
    int wr0 = (w >> 1) * 32, wc0 = (w & 1) * 64;
    int r0 = blockIdx.x * 64;

    if (t < 128) {
        float s = 0.f, qv = 0.f;
        #pragma unroll
        for (int k = 0; k < 8; ++k) {
            s  += stats[k * 256 + t];
            qv += stats[k * 256 + 128 + t];
        }
        float fn = (float)n;
        float mean = s / fn;
        float var = qv / fn - mean * mean;   // biased variance
        float istd = rsqrtf(var + 1e-5f);
        float a = gamma[t] * istd;
        abuf[t] = a;
        bbuf[t] = beta[t] - mean * a;
    }
    __syncthreads();   // abuf/bbuf visible to all

    fx4 acc[2][4];
    fx4 z4 = {0.f, 0.f, 0.f, 0.f};
    #pragma unroll
    for (int r = 0; r < 2; ++r)
        #pragma unroll
        for (int c = 0; c < 4; ++c) acc[r][c] = z4;

    for (int kt = 0; kt < 4; ++kt) {
        int kbase = kt * 32;
        __syncthreads();
        {
            int row = t >> 2, p = t & 3;
            int sl = p ^ ((row >> 1) & 3);
            int gr = r0 + row; gr = gr < n ? gr : (n - 1);
            GLL16(s1b + (size_t)gr * 128 + kbase + sl * 8, &xs[t * 8]);
            #pragma unroll
            for (int it = 0; it < 2; ++it) {
                int i = t + it * 256;
                int wrow = i >> 2, wp = i & 3;
                int wsl = wp ^ ((wrow >> 1) & 3);
                GLL16(wB2p + (size_t)wrow * 128 + kbase + wsl * 8, &ws[i * 8]);
            }
        }
        __syncthreads();   // DMA drained -> tiles visible
        int kb = kbase + q * 8;
        fx4 a0 = *(const fx4*)&abuf[kb];
        fx4 a1 = *(const fx4*)&abuf[kb + 4];
        fx4 b0 = *(const fx4*)&bbuf[kb];
        fx4 b1 = *(const fx4*)&bbuf[kb + 4];
        s8v af[2], bfr[4];
        #pragma unroll
        for (int r = 0; r < 2; ++r) {
            int row = wr0 + r * 16 + lm;
            s8v sv = *(const s8v*)&xs[row * 32 + ((q ^ ((row >> 1) & 3)) << 3)];
            union { s8v v; unsigned short u[8]; } o;
            #pragma unroll
            for (int u = 0; u < 4; ++u) {
                float h0 = fmaxf(fmaf(a0[u], bf2f((unsigned short)sv[u]), b0[u]), 0.f);
                float h1 = fmaxf(fmaf(a1[u], bf2f((unsigned short)sv[u + 4]), b1[u]), 0.f);
                o.u[u]     = f2bf(h0);
                o.u[u + 4] = f2bf(h1);
            }
            af[r] = o.v;
        }
        #pragma unroll
        for (int c = 0; c < 4; ++c) {
            int row = wc0 + c * 16 + lm;
            bfr[c] = *(const s8v*)&ws[row * 32 + ((q ^ ((row >> 1) & 3)) << 3)];
        }
        #pragma unroll
        for (int r = 0; r < 2; ++r)
            #pragma unroll
            for (int c = 0; c < 4; ++c)
                acc[r][c] = __builtin_amdgcn_mfma_f32_16x16x32_bf16(af[r], bfr[c], acc[r][c], 0, 0, 0);
    }

    // epilogue: y2b bf16 stride 64 (j<47) / rbuf fp32 stride 48 + b2l (j 47..93)
    #pragma unroll
    for (int c = 0; c < 4; ++c) {
        int col = wc0 + c * 16 + lm;
        float bb = (col >= 47 && col < 94) ? b2l[col - 47] : 0.f;
        #pragma unroll
        for (int r = 0; r < 2; ++r) {
            int rowb = wr0 + r * 16 + q * 4;
            #pragma unroll
            for (int i = 0; i < 4; ++i) {
                int gr = r0 + rowb + i;
                if (gr >= n) continue;
                float v = acc[r][c][i];
                if (col < 47)      y2b[(size_t)gr * 64 + col] = f2bf(v);
                else if (col < 94) rbuf[(size_t)gr * 48 + (col - 47)] = v + bb;
            }
        }
    }
}

// ---- layer-2 gather + combine + L2-norm. 16 lanes/node (lane owns 4 ch),
// 16 nodes/block, 8-edge unroll -> 4 independent load chains per wave.
__global__ __launch_bounds__(256) void k_gather2_final(
        const unsigned short* __restrict__ y2b, const float* __restrict__ rbuf,
        const int* __restrict__ rowStart, const int* __restrict__ deg,
        const int* __restrict__ srcIdx, float* __restrict__ out, int n) {
    int t = threadIdx.x;
    int q = t & 15, grp = t >> 4;
    int node = blockIdx.x * 16 + grp;
    if (node >= n) return;
    int beg = rowStart[node];
    int d = deg[node];
    int end = beg + d;
    float acc[4] = {0.f, 0.f, 0.f, 0.f};
    int e = beg;
    for (; e + 8 <= end; e += 8) {
        int s0 = srcIdx[e],     s1v = srcIdx[e + 1];
        int s2 = srcIdx[e + 2], s3  = srcIdx[e + 3];
        int s4 = srcIdx[e + 4], s5  = srcIdx[e + 5];
        int s6 = srcIdx[e + 6], s7  = srcIdx[e + 7];
        s4v v0 = *(const s4v*)(y2b + (size_t)s0 * 64 + q * 4);
        s4v v1 = *(const s4v*)(y2b + (size_t)s1v * 64 + q * 4);
        s4v v2 = *(const s4v*)(y2b + (size_t)s2 * 64 + q * 4);
        s4v v3 = *(const s4v*)(y2b + (size_t)s3 * 64 + q * 4);
        s4v v4 = *(const s4v*)(y2b + (size_t)s4 * 64 + q * 4);
        s4v v5 = *(const s4v*)(y2b + (size_t)s5 * 64 + q * 4);
        s4v v6 = *(const s4v*)(y2b + (size_t)s6 * 64 + q * 4);
        s4v v7 = *(const s4v*)(y2b + (size_t)s7 * 64 + q * 4);
        #pragma unroll
        for (int u = 0; u < 4; ++u) {
            acc[u] += (bf2f((unsigned short)v0[u]) + bf2f((unsigned short)v1[u]))
                    + (bf2f((unsigned short)v2[u]) + bf2f((unsigned short)v3[u]))
                    + (bf2f((unsigned short)v4[u]) + bf2f((unsigned short)v5[u]))
                    + (bf2f((unsigned short)v6[u]) + bf2f((unsigned short)v7[u]));
        }
    }
    for (; e + 4 <= end; e += 4) {
        int s0 = srcIdx[e],     s1v = srcIdx[e + 1];
        int s2 = srcIdx[e + 2], s3  = srcIdx[e + 3];
        s4v v0 = *(const s4v*)(y2b + (size_t)s0 * 64 + q * 4);
        s4v v1 = *(const s4v*)(y2b + (size_t)s1v * 64 + q * 4);
        s4v v2 = *(const s4v*)(y2b + (size_t)s2 * 64 + q * 4);
        s4v v3 = *(const s4v*)(y2b + (size_t)s3 * 64 + q * 4);
        #pragma unroll
        for (int u = 0; u < 4; ++u)
            acc[u] += (bf2f((unsigned short)v0[u]) + bf2f((unsigned short)v1[u]))
                    + (bf2f((unsigned short)v2[u]) + bf2f((unsigned short)v3[u]));
    }
    for (; e < end; ++e) {
        s4v v0 = *(const s4v*)(y2b + (size_t)srcIdx[e] * 64 + q * 4);
        #pragma unroll
        for (int u = 0; u < 4; ++u) acc[u] += bf2f((unsigned short)v0[u]);
    }
    float ic = 1.0f / fmaxf((float)d, 1.0f);
    fx4 rb = *(const fx4*)(rbuf + (size_t)node * 48 + q * 4);
    float vi[4];
    float ss = 0.f;
    #pragma unroll
    for (int u = 0; u < 4; ++u) {
        int ch = q * 4 + u;
        float v = (ch < 47) ? (acc[u] * ic + rb[u]) : 0.f;   // select masks pad (NaN-safe)
        vi[u] = v;
        ss += v * v;
    }
    #pragma unroll
    for (int off = 1; off <= 8; off <<= 1) ss += __shfl_xor(ss, off, 64);
    float inv = 1.0f / fmaxf(sqrtf(ss), 1e-12f);
    #pragma unroll
    for (int u = 0; u < 4; ++u) {
        int ch = q * 4 + u;
        if (ch < 47) out[(size_t)node * 47 + ch] = vi[u] * inv;
    }
}

extern "C" void kernel_launch(void* const* d_in, const int* in_sizes, int n_in,
                              void* d_out, int out_size, void* d_ws, size_t ws_size,
                              hipStream_t stream) {
    const float* x     = (const float*)d_in[0];
    const int*   ei    = (const int*)d_in[1];
    const float* w1l   = (const float*)d_in[2];
    const float* b1l   = (const float*)d_in[3];
    const float* w1r   = (const float*)d_in[4];
    const float* gamma = (const float*)d_in[5];
    const float* beta  = (const float*)d_in[6];
    const float* w2l   = (const float*)d_in[7];
    const float* b2l   = (const float*)d_in[8];
    const float* w2r   = (const float*)d_in[9];
    float* out = (float*)d_out;

    int n  = in_sizes[0] / 128;   // 100000
    int nE = in_sizes[1] / 2;     // 800000

    int NB  = (n + 255) >> 8;                    // 391 buckets
    int nCh = (nE + CSR_CHUNK - 1) / CSR_CHUNK;  // 98 chunks

    // ---- workspace layout ----
    // deg[n](int) | stats[2048](f32, 8 copies) | rowStart[n] | meta[n]
    // | srcIdx[nE] | xb[128n bf16] | aggb[128n bf16] | s1b[128n bf16]
    // | wB1 | wB2p
    // meta: counts[nCh*512] then bucketStart at +60000, gcur[512] at +61000,
    // done-counter at +61600.
    // pairs[nE] overlays s1b (dead until gemm1).
    // y2b[64n bf16, 1 line/row] + rbuf[48n f32] overlay xb+aggb.
    int* deg       = (int*)d_ws;
    float* stats   = (float*)(deg + n);
    int* rowStart  = (int*)(stats + 2048);
    int* meta      = rowStart + n;
    int* srcIdx    = meta + n;
    unsigned short* xb   = (unsigned short*)(srcIdx + nE);
    unsigned short* aggb = xb + (size_t)n * 128;
    unsigned short* s1b  = aggb + (size_t)n * 128;
    unsigned short* wB1  = s1b + (size_t)n * 128;
    unsigned short* wB2p = wB1 + 32768;
    int* counts      = meta;
    int* bucketStart = meta + 60000;
    int* gcur        = meta + 61000;
    int* done        = meta + 61600;
    int* pairs       = (int*)s1b;             // packed (src<<8)|(dst&255)
    unsigned short* y2b = xb;                 // stride 64 shorts (128B/row)
    float* rbuf = (float*)(y2b + (size_t)n * 64);   // stride 48 f32

    // 0: zero the last-block election counter (workspace is poisoned)
    hipMemsetAsync(done, 0, sizeof(int), stream);
    // 1: prep (bcount + bucket scan first | grid-stride xcast/weights/stats)
    k_prep<<<nCh + PREP_XBLOCKS, 256, 0, stream>>>(
        x, w1l, w1r, w2l, w2r, ei, xb, wB1, wB2p, stats, counts,
        bucketStart, gcur, done, n, nE, nCh, NB);
    // 2-3: CSR build (bucketed counting sort, runtime range reservation)
    k_bfill<<<nCh, 256, 0, stream>>>(ei, counts, gcur, pairs, nE);
    k_csr<<<NB, 256, 0, stream>>>(pairs, bucketStart, deg, rowStart, srcIdx, n);
    // 4-5: layer 1
    k_gather1<<<(n + 15) / 16, 256, 0, stream>>>(xb, rowStart, deg, srcIdx, aggb, n);
    k_gemm1<<<(n + 63) / 64, 256, 0, stream>>>(xb, aggb, wB1, b1l, s1b, stats, n);
    // 6-7: layer 2 (BN finalize inlined in gemm2)
    k_gemm2<<<(n + 63) / 64, 256, 0, stream>>>(
        s1b, wB2p, stats, gamma, beta, b2l, y2b, rbuf, n);
    k_gather2_final<<<(n + 15) / 16, 256, 0, stream>>>(y2b, rbuf, rowStart, deg, srcIdx, out, n);
}

// Round 16
// 250.646 us; speedup vs baseline: 1.0635x; 1.0426x over previous
//
#include <hip/hip_runtime.h>
#include <cstdint>

// GNN: 2-layer GraphSAGE (mean aggr, L2-normalize) + BatchNorm(train) + ReLU.
// N=100000 nodes, E=800000 edges, C: 128 -> 128 -> 47.
//
// Round 26: R25's bench run died on container acquisition (infra, not the
// kernel) -- resubmitting the identical R25 source. Rationale (from R24
// post-mortem): R24 raced under graph replay (post-timing absmax 0.45)
// because the elected-last-block scan read tot[] with PLAIN loads after
// other blocks' device-scope atomicAdds -- per-XCD L2 non-coherence (G16)
// can serve stale lines. Fix: move the scan behind a KERNEL BOUNDARY (the
// only sanctioned inter-workgroup visibility), keeping R24's win (the
// 98x512 column-sum deleted):
//  - k_prep hist blocks atomicAdd into global tot[512] only.
//  - tiny k_bmeta (1 block): read coherent tot, scan 512, write
//    bucketStart/gcur (~2-3us vs old 20us column-sum version).
//  - k_bfill recounts its own chunk (counts[] stays dead).
//  - memset zeroes tot[512] only.

typedef __attribute__((ext_vector_type(8))) short s8v;
typedef __attribute__((ext_vector_type(4))) short s4v;
typedef __attribute__((ext_vector_type(4))) float fx4;

#define CSR_CHUNK 8192
#define CSR_SH 8            // 256 nodes per bucket
#define CSR_NBPAD 512       // padded bucket count (NB = ceil(n/256) = 391)
#define CSR_BUFCAP 3072     // LDS srcbuf cap per bucket (mean 2046, +20 sigma)
#define PREP_XBLOCKS 1950   // persistent grid-stride blocks for elementwise

static __device__ __forceinline__ float bf2f(unsigned short h) {
    union { unsigned int u; float f; } c; c.u = (unsigned int)h << 16; return c.f;
}
static __device__ __forceinline__ unsigned short f2bf(float f) {
    union { float f; unsigned int u; } c; c.f = f;
    unsigned int u = c.u;
    return (unsigned short)((u + 0x7FFF + ((u >> 16) & 1)) >> 16);   // RNE
}

// ---- merged prep: bcount histograms -> global tot atomics, then
// grid-stride elementwise casts. No cross-block reads inside this kernel.
__global__ __launch_bounds__(256) void k_prep(
        const float* __restrict__ x, const float* __restrict__ w1l,
        const float* __restrict__ w1r, const float* __restrict__ w2l,
        const float* __restrict__ w2r, const int* __restrict__ ei,
        unsigned short* __restrict__ xb, unsigned short* __restrict__ wB1,
        unsigned short* __restrict__ wB2p, float* __restrict__ stats,
        int* __restrict__ tot, int n, int nE, int nCh) {
    __shared__ int hist[CSR_NBPAD];
    int t = threadIdx.x;
    if ((int)blockIdx.x < nCh) {
        int chunk = blockIdx.x;
        hist[t] = 0; hist[t + 256] = 0;
        __syncthreads();
        int e0 = chunk * CSR_CHUNK;
        int e1 = min(e0 + CSR_CHUNK, nE);
        for (int e = e0 + t; e < e1; e += 256)
            atomicAdd(&hist[ei[nE + e] >> CSR_SH], 1);
        __syncthreads();
        if (hist[t])       atomicAdd(&tot[t],       hist[t]);
        if (hist[t + 256]) atomicAdd(&tot[t + 256], hist[t + 256]);
        return;
    }
    // ---- grid-stride elementwise over the linear index space ----
    int nx = n * 16;
    int total = nx + 32768 + 16384 + 2048;
    int stride = (gridDim.x - nCh) * 256;
    for (int idx0 = ((int)blockIdx.x - nCh) * 256 + t; idx0 < total; idx0 += stride) {
        int idx = idx0;
        if (idx < nx) {
            float4 a = ((const float4*)x)[idx * 2];
            float4 b = ((const float4*)x)[idx * 2 + 1];
            union { s8v v; unsigned short u[8]; } o;
            o.u[0] = f2bf(a.x); o.u[1] = f2bf(a.y); o.u[2] = f2bf(a.z); o.u[3] = f2bf(a.w);
            o.u[4] = f2bf(b.x); o.u[5] = f2bf(b.y); o.u[6] = f2bf(b.z); o.u[7] = f2bf(b.w);
            ((s8v*)xb)[idx] = o.v;
            continue;
        }
        idx -= nx;
        if (idx < 32768) {
            int j = idx >> 8, k = idx & 255;
            float v = (k < 128) ? w1l[j * 128 + k] : w1r[j * 128 + (k - 128)];
            wB1[idx] = f2bf(v);
            continue;
        }
        idx -= 32768;
        if (idx < 16384) {
            int j = idx >> 7, k = idx & 127;
            float v = 0.f;
            if (j < 47)      v = w2l[j * 128 + k];
            else if (j < 94) v = w2r[(j - 47) * 128 + k];
            wB2p[idx] = f2bf(v);
            continue;
        }
        idx -= 16384;
        if (idx < 2048) stats[idx] = 0.f;   // 8-way split stats copies
    }
}

// ---- tiny bucket scan: 1 block, reads tot (coherent after kernel
// boundary), exclusive-scans 512 buckets, writes bucketStart + gcur.
__global__ __launch_bounds__(256) void k_bmeta(
        const int* __restrict__ tot, int* __restrict__ bucketStart,
        int* __restrict__ gcur, int NB) {
    __shared__ int tl[CSR_NBPAD], sh[256], bs[CSR_NBPAD];
    int t = threadIdx.x;
    tl[t] = tot[t];
    tl[t + 256] = tot[t + 256];
    __syncthreads();
    int pairSum = tl[2 * t] + tl[2 * t + 1];
    sh[t] = pairSum;
    __syncthreads();
    for (int off = 1; off < 256; off <<= 1) {
        int add = (t >= off) ? sh[t - off] : 0;
        __syncthreads();
        sh[t] += add;
        __syncthreads();
    }
    int excl = sh[t] - pairSum;
    bs[2 * t] = excl;
    bs[2 * t + 1] = excl + tl[2 * t];
    __syncthreads();
    for (int b = t; b <= NB; b += 256) bucketStart[b] = bs[b];
    for (int b = t; b < CSR_NBPAD; b += 256) gcur[b] = bs[b];
}

// k_bfill: recount own chunk's histogram (pass 1), reserve per-bucket
// ranges via gcur atomics, then scatter (pass 2).
__global__ __launch_bounds__(256) void k_bfill(
        const int* __restrict__ ei, int* __restrict__ gcur,
        int* __restrict__ pairs, int nE) {
    __shared__ int hist[CSR_NBPAD];
    __shared__ int cur[CSR_NBPAD];
    int t = threadIdx.x;
    hist[t] = 0; hist[t + 256] = 0;
    __syncthreads();
    int e0 = blockIdx.x * CSR_CHUNK;
    int e1 = min(e0 + CSR_CHUNK, nE);
    for (int e = e0 + t; e < e1; e += 256)
        atomicAdd(&hist[ei[nE + e] >> CSR_SH], 1);
    __syncthreads();
    #pragma unroll
    for (int i = 0; i < 2; ++i) {
        int b = t + i * 256;
        int h = hist[b];
        cur[b] = h ? atomicAdd(&gcur[b], h) : 0;
    }
    __syncthreads();
    for (int e = e0 + t; e < e1; e += 256) {
        int s = ei[e];
        int d = ei[nE + e];
        int p = atomicAdd(&cur[d >> CSR_SH], 1);
        pairs[p] = (s << 8) | (d & 255);
    }
}

__global__ __launch_bounds__(256) void k_csr(
        const int* __restrict__ pairs, const int* __restrict__ bucketStart,
        int* __restrict__ deg, int* __restrict__ rowStart,
        int* __restrict__ srcIdx, int n) {
    __shared__ int cnt[256], scn[256], cur[256];
    __shared__ int buf[CSR_BUFCAP];
    int t = threadIdx.x;
    int bkt = blockIdx.x;
    int eBeg = bucketStart[bkt], eEnd = bucketStart[bkt + 1];
    int node0 = bkt << CSR_SH;
    cnt[t] = 0;
    __syncthreads();
    for (int e = eBeg + t; e < eEnd; e += 256)
        atomicAdd(&cnt[pairs[e] & 255], 1);
    __syncthreads();
    int myc = cnt[t];
    scn[t] = myc;
    __syncthreads();
    for (int off = 1; off < 256; off <<= 1) {
        int add = (t >= off) ? scn[t - off] : 0;
        __syncthreads();
        scn[t] += add;
        __syncthreads();
    }
    int excl = scn[t] - myc;
    cur[t] = excl;
    int node = node0 + t;
    if (node < n) { deg[node] = myc; rowStart[node] = eBeg + excl; }
    __syncthreads();
    for (int e = eBeg + t; e < eEnd; e += 256) {
        int pk = pairs[e];
        int p = atomicAdd(&cur[pk & 255], 1);
        int src = pk >> 8;
        if (p < CSR_BUFCAP) buf[p] = src;
        else srcIdx[eBeg + p] = src;   // statistically never at this size
    }
    __syncthreads();
    int m = min(eEnd - eBeg, CSR_BUFCAP);
    for (int i = t; i < m; i += 256) srcIdx[eBeg + i] = buf[i];
}

// ---- layer-1 gather (bf16): 16 lanes/node, lane owns 8 ch; 4-edge unroll.
__global__ __launch_bounds__(256) void k_gather1(
        const unsigned short* __restrict__ xb, const int* __restrict__ rowStart,
        const int* __restrict__ deg, const int* __restrict__ srcIdx,
        unsigned short* __restrict__ aggb, int n) {
    int t = threadIdx.x;
    int q = t & 15, grp = t >> 4;
    int node = blockIdx.x * 16 + grp;
    if (node >= n) return;
    int beg = rowStart[node];
    int d = deg[node];
    int end = beg + d;
    float a0[8] = {}, a1[8] = {}, a2[8] = {}, a3[8] = {};
    int e = beg;
    for (; e + 4 <= end; e += 4) {
        int s0 = srcIdx[e], s1v = srcIdx[e + 1], s2 = srcIdx[e + 2], s3 = srcIdx[e + 3];
        s8v v0 = *(const s8v*)(xb + (size_t)s0 * 128 + q * 8);
        s8v v1 = *(const s8v*)(xb + (size_t)s1v * 128 + q * 8);
        s8v v2 = *(const s8v*)(xb + (size_t)s2 * 128 + q * 8);
        s8v v3 = *(const s8v*)(xb + (size_t)s3 * 128 + q * 8);
        #pragma unroll
        for (int u = 0; u < 8; ++u) {
            a0[u] += bf2f((unsigned short)v0[u]);
            a1[u] += bf2f((unsigned short)v1[u]);
            a2[u] += bf2f((unsigned short)v2[u]);
            a3[u] += bf2f((unsigned short)v3[u]);
        }
    }
    for (; e < end; ++e) {
        s8v v0 = *(const s8v*)(xb + (size_t)srcIdx[e] * 128 + q * 8);
        #pragma unroll
        for (int u = 0; u < 8; ++u) a0[u] += bf2f((unsigned short)v0[u]);
    }
    float ic = 1.0f / fmaxf((float)d, 1.0f);
    union { s8v v; unsigned short u[8]; } o;
    #pragma unroll
    for (int u = 0; u < 8; ++u)
        o.u[u] = f2bf((a0[u] + a1[u] + a2[u] + a3[u]) * ic);
    *(s8v*)(aggb + (size_t)node * 128 + q * 8) = o.v;
}

// Async 16B global->LDS (gfx950). Dest is wave-uniform base + lane*16;
// our LDS layout is lane-linear so per-lane dest == HW dest.
#define GLL16(GSRC, LDST) \
    __builtin_amdgcn_global_load_lds( \
        (__attribute__((address_space(1))) void*)(void*)(GSRC), \
        (__attribute__((address_space(3))) void*)(LDST), 16, 0, 0)

// ---- GEMM1 (bf16 MFMA): block 64x128, K=256 (aggb then xb), BK=32,
// 8 rounds. Grid 1563, launch_bounds(256,4) -> 4+ blocks/CU.
__global__ __launch_bounds__(256, 4) void k_gemm1(
        const unsigned short* __restrict__ xb, const unsigned short* __restrict__ aggb,
        const unsigned short* __restrict__ wB1, const float* __restrict__ b1l,
        unsigned short* __restrict__ s1b, float* __restrict__ stats, int n) {
    __shared__ __align__(16) unsigned short xs[64 * 32];    // 4KB [row][32]
    __shared__ __align__(16) unsigned short ws[128 * 32];   // 8KB [j][32]
    __shared__ float norm2[128];   // [64][2]
    __shared__ float invn[64];
    __shared__ float statS[256];   // [128][2]
    __shared__ float statQ[256];   // [128][2]
    int t = threadIdx.x;
    int w = t >> 6, L = t & 63;
    int q = L >> 4, lm = L & 15;
    int wr0 = (w >> 1) * 32;     // wave row base (0 or 32)
    int wc0 = (w & 1) * 64;      // wave col base (0 or 64)
    int r0 = blockIdx.x * 64;

    fx4 acc[2][4];
    fx4 z4 = {0.f, 0.f, 0.f, 0.f};
    #pragma unroll
    for (int r = 0; r < 2; ++r)
        #pragma unroll
        for (int c = 0; c < 4; ++c) acc[r][c] = z4;

    for (int kt = 0; kt < 8; ++kt) {
        const unsigned short* src = (kt < 4) ? aggb : xb;
        int kbase = (kt & 3) * 32;
        __syncthreads();   // previous round's reads done -> buffers reusable
        {
            // xs: 256 x 16B chunks (1/thread)
            int row = t >> 2, p = t & 3;
            int sl = p ^ ((row >> 1) & 3);
            int gr = r0 + row; gr = gr < n ? gr : (n - 1);
            GLL16(src + (size_t)gr * 128 + kbase + sl * 8, &xs[t * 8]);
            // ws: 512 x 16B chunks (2/thread)
            #pragma unroll
            for (int it = 0; it < 2; ++it) {
                int i = t + it * 256;
                int wrow = i >> 2, wp = i & 3;
                int wsl = wp ^ ((wrow >> 1) & 3);
                GLL16(wB1 + (size_t)wrow * 256 + kt * 32 + wsl * 8, &ws[i * 8]);
            }
        }
        __syncthreads();   // full vmcnt(0) drain before s_barrier -> DMA landed
        s8v af[2], bfr[4];
        #pragma unroll
        for (int r = 0; r < 2; ++r) {
            int row = wr0 + r * 16 + lm;
            af[r] = *(const s8v*)&xs[row * 32 + ((q ^ ((row >> 1) & 3)) << 3)];
        }
        #pragma unroll
        for (int c = 0; c < 4; ++c) {
            int row = wc0 + c * 16 + lm;
            bfr[c] = *(const s8v*)&ws[row * 32 + ((q ^ ((row >> 1) & 3)) << 3)];
        }
        #pragma unroll
        for (int r = 0; r < 2; ++r)
            #pragma unroll
            for (int c = 0; c < 4; ++c)
                acc[r][c] = __builtin_amdgcn_mfma_f32_16x16x32_bf16(af[r], bfr[c], acc[r][c], 0, 0, 0);
    }

    // ---- epilogue: bias -> row L2-norm -> scale -> bf16 store -> BN stats
    float bj[4];
    #pragma unroll
    for (int c = 0; c < 4; ++c) bj[c] = b1l[wc0 + c * 16 + lm];
    #pragma unroll
    for (int r = 0; r < 2; ++r)
        #pragma unroll
        for (int c = 0; c < 4; ++c) acc[r][c] += bj[c];

    fx4 pr[2];
    #pragma unroll
    for (int r = 0; r < 2; ++r) {
        fx4 p = acc[r][0] * acc[r][0];
        #pragma unroll
        for (int c = 1; c < 4; ++c) p += acc[r][c] * acc[r][c];
        #pragma unroll
        for (int off = 1; off <= 8; off <<= 1)
            #pragma unroll
            for (int i2 = 0; i2 < 4; ++i2) p[i2] += __shfl_xor(p[i2], off, 64);
        pr[r] = p;
    }

    __syncthreads();
    if (lm == 0) {
        #pragma unroll
        for (int r = 0; r < 2; ++r)
            #pragma unroll
            for (int i = 0; i < 4; ++i)
                norm2[(wr0 + r * 16 + q * 4 + i) * 2 + (w & 1)] = pr[r][i];
    }
    __syncthreads();
    if (t < 64) {
        float s = norm2[t * 2] + norm2[t * 2 + 1];
        invn[t] = 1.0f / fmaxf(sqrtf(s), 1e-12f);
    }
    __syncthreads();

    float cS[4] = {}, cQ[4] = {};
    #pragma unroll
    for (int r = 0; r < 2; ++r) {
        int rowb = wr0 + r * 16 + q * 4;
        fx4 iv = *(const fx4*)&invn[rowb];
        #pragma unroll
        for (int c = 0; c < 4; ++c) {
            fx4 v = acc[r][c] * iv;
            int col = wc0 + c * 16 + lm;
            #pragma unroll
            for (int i = 0; i < 4; ++i) {
                int gr = r0 + rowb + i;
                if (gr < n) {
                    s1b[(size_t)gr * 128 + col] = f2bf(v[i]);
                    cS[c] += v[i];
                    cQ[c] += v[i] * v[i];
                }
            }
        }
    }
    #pragma unroll
    for (int off = 16; off <= 32; off <<= 1)
        #pragma unroll
        for (int c = 0; c < 4; ++c) {
            cS[c] += __shfl_xor(cS[c], off, 64);
            cQ[c] += __shfl_xor(cQ[c], off, 64);
        }
    if (q == 0) {
        #pragma unroll
        for (int c = 0; c < 4; ++c) {
            int col = wc0 + c * 16 + lm;
            statS[col * 2 + (w >> 1)] = cS[c];
            statQ[col * 2 + (w >> 1)] = cQ[c];
        }
    }
    __syncthreads();
    if (t < 128) {
        float* sp = stats + ((int)blockIdx.x & 7) * 256;   // 8-way split
        atomicAdd(&sp[t],       statS[t * 2] + statS[t * 2 + 1]);
        atomicAdd(&sp[128 + t], statQ[t * 2] + statQ[t * 2 + 1]);
    }
}

// ---- GEMM2 (bf16 MFMA) with inline BN finalize. Block 64x128, BK=32,
// 4 rounds, grid 1563, launch_bounds(256,4). BN coeffs from 8 split copies.
__global__ __launch_bounds__(256, 4) void k_gemm2(
        const unsigned short* __restrict__ s1b, const unsigned short* __restrict__ wB2p,
        const float* __restrict__ stats, const float* __restrict__ gamma,
        const float* __restrict__ beta, const float* __restrict__ b2l,
        unsigned short* __restrict__ y2b, float* __restrict__ rbuf, int n) {
    __shared__ __align__(16) unsigned short xs[64 * 32];    // 4KB
    __shared__ __align__(16) unsigned short ws[128 * 32];   // 8KB
    __shared__ __align__(16) float abuf[128];
    __shared__ __align__(16) float bbuf[128];
    int t = threadIdx.x;
    int w = t >> 6, L = t & 63;
    int q = L >> 4, lm = L & 15;
    int wr0 = (w >> 1) * 32, wc0 = (w & 1) * 64;
    int r0 = blockIdx.x * 64;

    if (t < 128) {
        float s = 0.f, qv = 0.f;
        #pragma unroll
        for (int k = 0; k < 8; ++k) {
            s  += stats[k * 256 + t];
            qv += stats[k * 256 + 128 + t];
        }
        float fn = (float)n;
        float mean = s / fn;
        float var = qv / fn - mean * mean;   // biased variance
        float istd = rsqrtf(var + 1e-5f);
        float a = gamma[t] * istd;
        abuf[t] = a;
        bbuf[t] = beta[t] - mean * a;
    }
    __syncthreads();   // abuf/bbuf visible to all

    fx4 acc[2][4];
    fx4 z4 = {0.f, 0.f, 0.f, 0.f};
    #pragma unroll
    for (int r = 0; r < 2; ++r)
        #pragma unroll
        for (int c = 0; c < 4; ++c) acc[r][c] = z4;

    for (int kt = 0; kt < 4; ++kt) {
        int kbase = kt * 32;
        __syncthreads();
        {
            int row = t >> 2, p = t & 3;
            int sl = p ^ ((row >> 1) & 3);
            int gr = r0 + row; gr = gr < n ? gr : (n - 1);
            GLL16(s1b + (size_t)gr * 128 + kbase + sl * 8, &xs[t * 8]);
            #pragma unroll
            for (int it = 0; it < 2; ++it) {
                int i = t + it * 256;
                int wrow = i >> 2, wp = i & 3;
                int wsl = wp ^ ((wrow >> 1) & 3);
                GLL16(wB2p + (size_t)wrow * 128 + kbase + wsl * 8, &ws[i * 8]);
            }
        }
        __syncthreads();   // DMA drained -> tiles visible
        int kb = kbase + q * 8;
        fx4 a0 = *(const fx4*)&abuf[kb];
        fx4 a1 = *(const fx4*)&abuf[kb + 4];
        fx4 b0 = *(const fx4*)&bbuf[kb];
        fx4 b1 = *(const fx4*)&bbuf[kb + 4];
        s8v af[2], bfr[4];
        #pragma unroll
        for (int r = 0; r < 2; ++r) {
            int row = wr0 + r * 16 + lm;
            s8v sv = *(const s8v*)&xs[row * 32 + ((q ^ ((row >> 1) & 3)) << 3)];
            union { s8v v; unsigned short u[8]; } o;
            #pragma unroll
            for (int u = 0; u < 4; ++u) {
                float h0 = fmaxf(fmaf(a0[u], bf2f((unsigned short)sv[u]), b0[u]), 0.f);
                float h1 = fmaxf(fmaf(a1[u], bf2f((unsigned short)sv[u + 4]), b1[u]), 0.f);
                o.u[u]     = f2bf(h0);
                o.u[u + 4] = f2bf(h1);
            }
            af[r] = o.v;
        }
        #pragma unroll
        for (int c = 0; c < 4; ++c) {
            int row = wc0 + c * 16 + lm;
            bfr[c] = *(const s8v*)&ws[row * 32 + ((q ^ ((row >> 1) & 3)) << 3)];
        }
        #pragma unroll
        for (int r = 0; r < 2; ++r)
            #pragma unroll
            for (int c = 0; c < 4; ++c)
                acc[r][c] = __builtin_amdgcn_mfma_f32_16x16x32_bf16(af[r], bfr[c], acc[r][c], 0, 0, 0);
    }

    // epilogue: y2b bf16 stride 64 (j<47) / rbuf fp32 stride 48 + b2l (j 47..93)
    #pragma unroll
    for (int c = 0; c < 4; ++c) {
        int col = wc0 + c * 16 + lm;
        float bb = (col >= 47 && col < 94) ? b2l[col - 47] : 0.f;
        #pragma unroll
        for (int r = 0; r < 2; ++r) {
            int rowb = wr0 + r * 16 + q * 4;
            #pragma unroll
            for (int i = 0; i < 4; ++i) {
                int gr = r0 + rowb + i;
                if (gr >= n) continue;
                float v = acc[r][c][i];
                if (col < 47)      y2b[(size_t)gr * 64 + col] = f2bf(v);
                else if (col < 94) rbuf[(size_t)gr * 48 + (col - 47)] = v + bb;
            }
        }
    }
}

// ---- layer-2 gather + combine + L2-norm. 16 lanes/node (lane owns 4 ch),
// 16 nodes/block, 8-edge unroll -> 4 independent load chains per wave.
__global__ __launch_bounds__(256) void k_gather2_final(
        const unsigned short* __restrict__ y2b, const float* __restrict__ rbuf,
        const int* __restrict__ rowStart, const int* __restrict__ deg,
        const int* __restrict__ srcIdx, float* __restrict__ out, int n) {
    int t = threadIdx.x;
    int q = t & 15, grp = t >> 4;
    int node = blockIdx.x * 16 + grp;
    if (node >= n) return;
    int beg = rowStart[node];
    int d = deg[node];
    int end = beg + d;
    float acc[4] = {0.f, 0.f, 0.f, 0.f};
    int e = beg;
    for (; e + 8 <= end; e += 8) {
        int s0 = srcIdx[e],     s1v = srcIdx[e + 1];
        int s2 = srcIdx[e + 2], s3  = srcIdx[e + 3];
        int s4 = srcIdx[e + 4], s5  = srcIdx[e + 5];
        int s6 = srcIdx[e + 6], s7  = srcIdx[e + 7];
        s4v v0 = *(const s4v*)(y2b + (size_t)s0 * 64 + q * 4);
        s4v v1 = *(const s4v*)(y2b + (size_t)s1v * 64 + q * 4);
        s4v v2 = *(const s4v*)(y2b + (size_t)s2 * 64 + q * 4);
        s4v v3 = *(const s4v*)(y2b + (size_t)s3 * 64 + q * 4);
        s4v v4 = *(const s4v*)(y2b + (size_t)s4 * 64 + q * 4);
        s4v v5 = *(const s4v*)(y2b + (size_t)s5 * 64 + q * 4);
        s4v v6 = *(const s4v*)(y2b + (size_t)s6 * 64 + q * 4);
        s4v v7 = *(const s4v*)(y2b + (size_t)s7 * 64 + q * 4);
        #pragma unroll
        for (int u = 0; u < 4; ++u) {
            acc[u] += (bf2f((unsigned short)v0[u]) + bf2f((unsigned short)v1[u]))
                    + (bf2f((unsigned short)v2[u]) + bf2f((unsigned short)v3[u]))
                    + (bf2f((unsigned short)v4[u]) + bf2f((unsigned short)v5[u]))
                    + (bf2f((unsigned short)v6[u]) + bf2f((unsigned short)v7[u]));
        }
    }
    for (; e + 4 <= end; e += 4) {
        int s0 = srcIdx[e],     s1v = srcIdx[e + 1];
        int s2 = srcIdx[e + 2], s3  = srcIdx[e + 3];
        s4v v0 = *(const s4v*)(y2b + (size_t)s0 * 64 + q * 4);
        s4v v1 = *(const s4v*)(y2b + (size_t)s1v * 64 + q * 4);
        s4v v2 = *(const s4v*)(y2b + (size_t)s2 * 64 + q * 4);
        s4v v3 = *(const s4v*)(y2b + (size_t)s3 * 64 + q * 4);
        #pragma unroll
        for (int u = 0; u < 4; ++u)
            acc[u] += (bf2f((unsigned short)v0[u]) + bf2f((unsigned short)v1[u]))
                    + (bf2f((unsigned short)v2[u]) + bf2f((unsigned short)v3[u]));
    }
    for (; e < end; ++e) {
        s4v v0 = *(const s4v*)(y2b + (size_t)srcIdx[e] * 64 + q * 4);
        #pragma unroll
        for (int u = 0; u < 4; ++u) acc[u] += bf2f((unsigned short)v0[u]);
    }
    float ic = 1.0f / fmaxf((float)d, 1.0f);
    fx4 rb = *(const fx4*)(rbuf + (size_t)node * 48 + q * 4);
    float vi[4];
    float ss = 0.f;
    #pragma unroll
    for (int u = 0; u < 4; ++u) {
        int ch = q * 4 + u;
        float v = (ch < 47) ? (acc[u] * ic + rb[u]) : 0.f;   // select masks pad (NaN-safe)
        vi[u] = v;
        ss += v * v;
    }
    #pragma unroll
    for (int off = 1; off <= 8; off <<= 1) ss += __shfl_xor(ss, off, 64);
    float inv = 1.0f / fmaxf(sqrtf(ss), 1e-12f);
    #pragma unroll
    for (int u = 0; u < 4; ++u) {
        int ch = q * 4 + u;
        if (ch < 47) out[(size_t)node * 47 + ch] = vi[u] * inv;
    }
}

extern "C" void kernel_launch(void* const* d_in, const int* in_sizes, int n_in,
                              void* d_out, int out_size, void* d_ws, size_t ws_size,
                              hipStream_t stream) {
    const float* x     = (const float*)d_in[0];
    const int*   ei    = (const int*)d_in[1];
    const float* w1l   = (const float*)d_in[2];
    const float* b1l   = (const float*)d_in[3];
    const float* w1r   = (const float*)d_in[4];
    const float* gamma = (const float*)d_in[5];
    const float* beta  = (const float*)d_in[6];
    const float* w2l   = (const float*)d_in[7];
    const float* b2l   = (const float*)d_in[8];
    const float* w2r   = (const float*)d_in[9];
    float* out = (float*)d_out;

    int n  = in_sizes[0] / 128;   // 100000
    int nE = in_sizes[1] / 2;     // 800000

    int NB  = (n + 255) >> 8;                    // 391 buckets
    int nCh = (nE + CSR_CHUNK - 1) / CSR_CHUNK;  // 98 chunks

    // ---- workspace layout ----
    // deg[n](int) | stats[2048](f32, 8 copies) | rowStart[n] | meta[n]
    // | srcIdx[nE] | xb[128n bf16] | aggb[128n bf16] | s1b[128n bf16]
    // | wB1 | wB2p
    // meta: bucketStart at +60000, gcur[512] at +61000, tot[512] at +61600.
    // pairs[nE] overlays s1b (dead until gemm1).
    // y2b[64n bf16, 1 line/row] + rbuf[48n f32] overlay xb+aggb.
    int* deg       = (int*)d_ws;
    float* stats   = (float*)(deg + n);
    int* rowStart  = (int*)(stats + 2048);
    int* meta      = rowStart + n;
    int* srcIdx    = meta + n;
    unsigned short* xb   = (unsigned short*)(srcIdx + nE);
    unsigned short* aggb = xb + (size_t)n * 128;
    unsigned short* s1b  = aggb + (size_t)n * 128;
    unsigned short* wB1  = s1b + (size_t)n * 128;
    unsigned short* wB2p = wB1 + 32768;
    int* bucketStart = meta + 60000;
    int* gcur        = meta + 61000;
    int* tot         = meta + 61600;
    int* pairs       = (int*)s1b;             // packed (src<<8)|(dst&255)
    unsigned short* y2b = xb;                 // stride 64 shorts (128B/row)
    float* rbuf = (float*)(y2b + (size_t)n * 64);   // stride 48 f32

    // 0: zero bucket totals (workspace is poisoned)
    hipMemsetAsync(tot, 0, CSR_NBPAD * sizeof(int), stream);
    // 1: prep (bcount -> tot atomics | grid-stride casts/stats zero)
    k_prep<<<nCh + PREP_XBLOCKS, 256, 0, stream>>>(
        x, w1l, w1r, w2l, w2r, ei, xb, wB1, wB2p, stats, tot, n, nE, nCh);
    // 2: tiny bucket scan (kernel boundary guarantees tot visibility)
    k_bmeta<<<1, 256, 0, stream>>>(tot, bucketStart, gcur, NB);
    // 3-4: CSR build (recount + runtime range reservation, then sort)
    k_bfill<<<nCh, 256, 0, stream>>>(ei, gcur, pairs, nE);
    k_csr<<<NB, 256, 0, stream>>>(pairs, bucketStart, deg, rowStart, srcIdx, n);
    // 5-6: layer 1
    k_gather1<<<(n + 15) / 16, 256, 0, stream>>>(xb, rowStart, deg, srcIdx, aggb, n);
    k_gemm1<<<(n + 63) / 64, 256, 0, stream>>>(xb, aggb, wB1, b1l, s1b, stats, n);
    // 7-8: layer 2 (BN finalize inlined in gemm2)
    k_gemm2<<<(n + 63) / 64, 256, 0, stream>>>(
        s1b, wB2p, stats, gamma, beta, b2l, y2b, rbuf, n);
    k_gather2_final<<<(n + 15) / 16, 256, 0, stream>>>(y2b, rbuf, rowStart, deg, srcIdx, out, n);
}